// Round 13
// baseline (404.722 us; speedup 1.0000x reference)
//
#include <hip/hip_runtime.h>

#define NI 50000
#define NL 400000
#define EPO 400000
#define EADJ 200000

// encoder tiling
#define K1_ITER 8
#define K2_ITER 4
#define K1_ROWS (32*K1_ITER)   // 256 rows/block
#define K2_ROWS (32*K2_ITER)   // 128 rows/block
#define NLB ((NL + K1_ROWS - 1)/K1_ROWS)   // 1563
#define NIB ((NI + K2_ROWS - 1)/K2_ROWS)   // 391
#define NHB ((EPO + EADJ + 255)/256)       // 2344 histogram blocks

typedef unsigned int u32;
typedef unsigned short u16;
typedef short bf16x8 __attribute__((ext_vector_type(8)));
typedef float f32x4 __attribute__((ext_vector_type(4)));

__device__ __forceinline__ float bf2f(u16 h){ return __uint_as_float(((u32)h)<<16); }
__device__ __forceinline__ u16 f2bf(float f){
  u32 u = __float_as_uint(f);
  u += 0x7FFFu + ((u>>16)&1u);
  return (u16)(u>>16);
}
__device__ __forceinline__ u32 pack2(float a, float b){
  return (u32)f2bf(a) | ((u32)f2bf(b)<<16);
}

// GRU combined weight value: maps [inter(256) | h0(64)] -> [r_sum, z_sum, i_n, h_n]
__device__ __forceinline__ float b2_val(
    const float* __restrict__ W_ih, const float* __restrict__ W_hh, int m, int k)
{
  if(k < 256){ return (m<192) ? W_ih[m*256+k] : 0.f; }
  int kk = k-256;
  if(m<128) return W_hh[m*64+kk];
  if(m>=192) return W_hh[(m-64)*64+kk];
  return 0.f;
}

// ---------------- K0: weight prep + cnt zeroing ----------------
// WheadF: head-projection B in MFMA fragment order:
//   u4 index = ((h*4+kt)*4+ct)*64 + lane, 8 bf16 each
//   value = B[n=ct*16+(lane&15)][k'=kt*32+(lane>>4)*8+j]
//   k'<64 -> Wsrc_po[k'][h*64+n] ; else Wsrc_adj[k'-64][h*64+n]
__global__ __launch_bounds__(256) void k0_prep(
    const float* __restrict__ Wsrc_po, const float* __restrict__ att_src_po,
    const float* __restrict__ Wdst_po, const float* __restrict__ att_dst_po,
    const float* __restrict__ Wsrc_adj, const float* __restrict__ att_src_adj,
    const float* __restrict__ Wdst_adj, const float* __restrict__ att_dst_adj,
    const float* __restrict__ W_ih, const float* __restrict__ W_hh,
    const float* __restrict__ bias_po, const float* __restrict__ bias_adj,
    const float* __restrict__ b_ih, const float* __restrict__ b_hh,
    float* __restrict__ v4, u16* __restrict__ WheadF, u16* __restrict__ B2F,
    float* __restrict__ bias_comb, float* __restrict__ bias2,
    int* __restrict__ cnt)
{
  const int T0 = 1024, T1 = 4*4*4*64*8, T2 = 10*16*64*8;
  const int TC = 2*NI;
  int total = T0 + T1 + T2 + 256 + 256 + TC;
  for(int t = blockIdx.x*256 + threadIdx.x; t < total; t += gridDim.x*256){
    if(t < T0){
      int which = t>>8, hc = t&255, h = hc>>6, c = hc&63;
      const float *W, *att;
      if(which==0){ W=Wsrc_po;  att=att_src_po; }
      else if(which==1){ W=Wdst_po;  att=att_dst_po; }
      else if(which==2){ W=Wsrc_adj; att=att_src_adj; }
      else { W=Wdst_adj; att=att_dst_adj; }
      float s=0.f;
      for(int j=0;j<64;j++) s += W[c*256 + h*64 + j]*att[h*64+j];
      v4[which*256 + hc] = s;
    } else if(t < T0 + T1){
      int i = t - T0;
      int j = i&7;
      int u4 = i>>3;
      int lane = u4&63;
      int rem = u4>>6;          // h*16 + kt*4 + ct
      int ct = rem&3, kt = (rem>>2)&3, h = rem>>4;
      int r = lane&15, qb = lane>>4;
      int kp = kt*32 + qb*8 + j;
      int n = ct*16 + r;
      float val = (kp<64) ? Wsrc_po[kp*256 + h*64 + n]
                          : Wsrc_adj[(kp-64)*256 + h*64 + n];
      WheadF[i] = f2bf(val);
    } else if(t < T0 + T1 + T2){
      int i = t - (T0+T1);
      int j = i&7;
      int u4 = i>>3;
      int kstep = u4>>10, rem = u4&1023, tile = rem>>6, lane = rem&63;
      int col = tile*16 + (lane&15);
      int k = kstep*32 + (lane>>4)*8 + j;
      B2F[i] = f2bf(b2_val(W_ih, W_hh, col, k));
    } else if(t < T0 + T1 + T2 + 256){
      int m = t - (T0+T1+T2);
      bias_comb[m] = bias_po[m] + bias_adj[m];
    } else if(t < T0 + T1 + T2 + 512){
      int m = t - (T0+T1+T2+256);
      float v;
      if(m<128) v = b_ih[m] + b_hh[m];
      else if(m<192) v = b_ih[m];
      else v = b_hh[m-64];
      bias2[m] = v;
    } else {
      cnt[t - (T0+T1+T2+512)] = 0;
    }
  }
}

// ---------------- K_ENC: fused lane+int encoders + edge histogram (unchanged) ----------------
__global__ __launch_bounds__(256) void k_enc(
    const float* __restrict__ x_lane, const float* __restrict__ Wl, const float* __restrict__ bl,
    const float* __restrict__ x_int,  const float* __restrict__ Wi, const float* __restrict__ bi,
    const float* __restrict__ v_sp, const float* __restrict__ v_dp,
    const float* __restrict__ v_sa, const float* __restrict__ v_da,
    u16* __restrict__ e_lane, float* __restrict__ a_s_po,
    u16* __restrict__ e_int, float* __restrict__ a_dp, float* __restrict__ a_sa,
    float* __restrict__ a_da,
    const int* __restrict__ dst_po, const int* __restrict__ dst_adj,
    int* __restrict__ cnt)
{
  int t = threadIdx.x;
  int wv = t>>6, l = t&63;
  int g = l&7, m = l>>3;
  int blk = blockIdx.x;
  if(blk < NLB){
    float wreg[12][8], breg[8];
#pragma unroll
    for(int k=0;k<12;k++){
      float4 w0 = *(const float4*)(Wl + k*64 + g*8);
      float4 w1 = *(const float4*)(Wl + k*64 + g*8 + 4);
      wreg[k][0]=w0.x; wreg[k][1]=w0.y; wreg[k][2]=w0.z; wreg[k][3]=w0.w;
      wreg[k][4]=w1.x; wreg[k][5]=w1.y; wreg[k][6]=w1.z; wreg[k][7]=w1.w;
    }
    {
      float4 b0 = *(const float4*)(bl + g*8);
      float4 b1 = *(const float4*)(bl + g*8 + 4);
      breg[0]=b0.x; breg[1]=b0.y; breg[2]=b0.z; breg[3]=b0.w;
      breg[4]=b1.x; breg[5]=b1.y; breg[6]=b1.z; breg[7]=b1.w;
    }
    int rowbase = blk*K1_ROWS + wv*(8*K1_ITER) + m;
    float4 Aa={0,0,0,0}, Ab={0,0,0,0}, Ac={0,0,0,0};
    float4 Ba={0,0,0,0}, Bb={0,0,0,0}, Bc={0,0,0,0};
    if(rowbase < NL){
      const float4* xp = (const float4*)(x_lane + (size_t)rowbase*12);
      Aa = xp[0]; Ab = xp[1]; Ac = xp[2];
    }
    if(rowbase+8 < NL){
      const float4* xp = (const float4*)(x_lane + (size_t)(rowbase+8)*12);
      Ba = xp[0]; Bb = xp[1]; Bc = xp[2];
    }
#pragma unroll
    for(int it=0; it<K1_ITER; it++){
      int row = rowbase + it*8;
      float4 Ca={0,0,0,0}, Cb={0,0,0,0}, Cc={0,0,0,0};
      if(it+2 < K1_ITER && row+16 < NL){
        const float4* xp = (const float4*)(x_lane + (size_t)(row+16)*12);
        Ca = xp[0]; Cb = xp[1]; Cc = xp[2];
      }
      float xv[12];
      xv[0]=Aa.x; xv[1]=Aa.y; xv[2]=Aa.z; xv[3]=Aa.w;
      xv[4]=Ab.x; xv[5]=Ab.y; xv[6]=Ab.z; xv[7]=Ab.w;
      xv[8]=Ac.x; xv[9]=Ac.y; xv[10]=Ac.z; xv[11]=Ac.w;
      float acc[8];
#pragma unroll
      for(int j=0;j<8;j++) acc[j]=breg[j];
#pragma unroll
      for(int k=0;k<12;k++){
        float xk = xv[k];
#pragma unroll
        for(int j=0;j<8;j++) acc[j] += xk*wreg[k][j];
      }
      float e[8];
#pragma unroll
      for(int j=0;j<8;j++) e[j] = fmaxf(acc[j], 0.f);
      float as[4];
#pragma unroll
      for(int h=0;h<4;h++){
        float4 v0 = *(const float4*)(v_sp + h*64 + g*8);
        float4 v1 = *(const float4*)(v_sp + h*64 + g*8 + 4);
        as[h] = e[0]*v0.x + e[1]*v0.y + e[2]*v0.z + e[3]*v0.w
              + e[4]*v1.x + e[5]*v1.y + e[6]*v1.z + e[7]*v1.w;
      }
#pragma unroll
      for(int o=1;o<8;o<<=1){
#pragma unroll
        for(int h=0;h<4;h++) as[h] += __shfl_xor(as[h], o, 64);
      }
      if(row < NL){
        uint4 P;
        P.x = pack2(e[0],e[1]); P.y = pack2(e[2],e[3]);
        P.z = pack2(e[4],e[5]); P.w = pack2(e[6],e[7]);
        ((uint4*)e_lane)[(size_t)row*8 + g] = P;
        if(g==0){
          float4 A; A.x=as[0]; A.y=as[1]; A.z=as[2]; A.w=as[3];
          *(float4*)(a_s_po + (size_t)row*4) = A;
        }
      }
      Aa=Ba; Ab=Bb; Ac=Bc;
      Ba=Ca; Bb=Cb; Bc=Cc;
    }
  } else if(blk < NLB + NIB){
    int b2 = blk - NLB;
    float breg[8];
    {
      float4 b0 = *(const float4*)(bi + g*8);
      float4 b1 = *(const float4*)(bi + g*8 + 4);
      breg[0]=b0.x; breg[1]=b0.y; breg[2]=b0.z; breg[3]=b0.w;
      breg[4]=b1.x; breg[5]=b1.y; breg[6]=b1.z; breg[7]=b1.w;
    }
    int rowbase = b2*K2_ROWS + wv*(8*K2_ITER) + m;
#pragma unroll
    for(int it=0; it<K2_ITER; it++){
      int row = rowbase + it*8;
      float xv[16];
      if(row < NI){
        const float4* xp = (const float4*)(x_int + (size_t)row*16);
#pragma unroll
        for(int q=0;q<4;q++){
          float4 xq = xp[q];
          xv[q*4]=xq.x; xv[q*4+1]=xq.y; xv[q*4+2]=xq.z; xv[q*4+3]=xq.w;
        }
      } else {
#pragma unroll
        for(int k=0;k<16;k++) xv[k]=0.f;
      }
      float acc[8];
#pragma unroll
      for(int j=0;j<8;j++) acc[j]=breg[j];
#pragma unroll
      for(int k=0;k<16;k++){
        float4 w0 = *(const float4*)(Wi + k*64 + g*8);
        float4 w1 = *(const float4*)(Wi + k*64 + g*8 + 4);
        float xk = xv[k];
        acc[0] += xk*w0.x; acc[1] += xk*w0.y; acc[2] += xk*w0.z; acc[3] += xk*w0.w;
        acc[4] += xk*w1.x; acc[5] += xk*w1.y; acc[6] += xk*w1.z; acc[7] += xk*w1.w;
      }
      float e[8];
#pragma unroll
      for(int j=0;j<8;j++) e[j] = fmaxf(acc[j], 0.f);
      float ad[4], sa[4], da[4];
#pragma unroll
      for(int h=0;h<4;h++){
        float4 v0, v1;
        v0 = *(const float4*)(v_dp + h*64 + g*8); v1 = *(const float4*)(v_dp + h*64 + g*8 + 4);
        ad[h] = e[0]*v0.x + e[1]*v0.y + e[2]*v0.z + e[3]*v0.w
              + e[4]*v1.x + e[5]*v1.y + e[6]*v1.z + e[7]*v1.w;
        v0 = *(const float4*)(v_sa + h*64 + g*8); v1 = *(const float4*)(v_sa + h*64 + g*8 + 4);
        sa[h] = e[0]*v0.x + e[1]*v0.y + e[2]*v0.z + e[3]*v0.w
              + e[4]*v1.x + e[5]*v1.y + e[6]*v1.z + e[7]*v1.w;
        v0 = *(const float4*)(v_da + h*64 + g*8); v1 = *(const float4*)(v_da + h*64 + g*8 + 4);
        da[h] = e[0]*v0.x + e[1]*v0.y + e[2]*v0.z + e[3]*v0.w
              + e[4]*v1.x + e[5]*v1.y + e[6]*v1.z + e[7]*v1.w;
      }
#pragma unroll
      for(int o=1;o<8;o<<=1){
#pragma unroll
        for(int h=0;h<4;h++){
          ad[h] += __shfl_xor(ad[h], o, 64);
          sa[h] += __shfl_xor(sa[h], o, 64);
          da[h] += __shfl_xor(da[h], o, 64);
        }
      }
      if(row < NI){
        uint4 P;
        P.x = pack2(e[0],e[1]); P.y = pack2(e[2],e[3]);
        P.z = pack2(e[4],e[5]); P.w = pack2(e[6],e[7]);
        ((uint4*)e_int)[(size_t)row*8 + g] = P;
        if(g==0){
          float4 A;
          A.x=ad[0]; A.y=ad[1]; A.z=ad[2]; A.w=ad[3]; *(float4*)(a_dp + (size_t)row*4) = A;
          A.x=sa[0]; A.y=sa[1]; A.z=sa[2]; A.w=sa[3]; *(float4*)(a_sa + (size_t)row*4) = A;
          A.x=da[0]; A.y=da[1]; A.z=da[2]; A.w=da[3]; *(float4*)(a_da + (size_t)row*4) = A;
        }
      }
    }
  } else {
    int i = (blk - NLB - NIB)*256 + t;
    if(i < EPO) atomicAdd(&cnt[dst_po[i]], 1);
    else if(i < EPO+EADJ) atomicAdd(&cnt[NI + dst_adj[i-EPO]], 1);
  }
}

// ---------------- K4: parallel 3-phase scan ----------------
__global__ __launch_bounds__(1024) void k4a_scan(
    const int* __restrict__ cnt, int* __restrict__ offA, int* __restrict__ bsum)
{
  __shared__ int s[1024];
  int y = blockIdx.y;
  int i = blockIdx.x*1024 + threadIdx.x;
  int v = (i<NI) ? cnt[y*NI+i] : 0;
  s[threadIdx.x]=v;
  __syncthreads();
  for(int o=1;o<1024;o<<=1){
    int t = (threadIdx.x>=o) ? s[threadIdx.x-o] : 0;
    __syncthreads();
    s[threadIdx.x] += t;
    __syncthreads();
  }
  if(i<NI) offA[y*NI+i] = s[threadIdx.x]-v;
  if(threadIdx.x==1023) bsum[y*64+blockIdx.x] = s[1023];
}

__global__ __launch_bounds__(128) void k4b_scanb(int* __restrict__ bsum)
{
  int y = threadIdx.x>>6, lane = threadIdx.x&63;
  int v = (lane<49) ? bsum[y*64+lane] : 0;
  int orig = v;
#pragma unroll
  for(int o=1;o<64;o<<=1){
    int t = __shfl_up(v,o,64);
    if(lane>=o) v += t;
  }
  if(lane<49) bsum[y*64+lane] = v-orig;
}

__global__ __launch_bounds__(1024) void k4c_add(
    int* __restrict__ offA, int* __restrict__ cur, const int* __restrict__ bsum)
{
  int y = blockIdx.y;
  int i = blockIdx.x*1024 + threadIdx.x;
  if(i<NI){
    int o = offA[y*NI+i] + bsum[y*64+blockIdx.x];
    offA[y*NI+i]=o;
    cur[y*NI+i]=o;
  }
}

// ---------------- K5: scatter src + per-edge softmax numerator weights ----------------
__global__ __launch_bounds__(256) void k5_scatter(
    const int* __restrict__ src_po, const int* __restrict__ dst_po,
    const int* __restrict__ src_adj, const int* __restrict__ dst_adj,
    const float* __restrict__ a_s_po, const float* __restrict__ a_d_po,
    const float* __restrict__ a_s_adj, const float* __restrict__ a_d_adj,
    int* __restrict__ cur, int* __restrict__ csr_po, int* __restrict__ csr_adj,
    float* __restrict__ pw_po, float* __restrict__ pw_adj)
{
  int i = blockIdx.x*256 + threadIdx.x;
  if(i < EPO){
    int s = src_po[i];
    int d = dst_po[i];
    int p = atomicAdd(&cur[d],1);
    csr_po[p] = s;
    float4 as = *(const float4*)(a_s_po + (size_t)s*4);
    float4 ad = *(const float4*)(a_d_po + (size_t)d*4);
    float4 pv;
    float x;
    x = as.x+ad.x; pv.x = __expf(x>0.f?x:0.2f*x);
    x = as.y+ad.y; pv.y = __expf(x>0.f?x:0.2f*x);
    x = as.z+ad.z; pv.z = __expf(x>0.f?x:0.2f*x);
    x = as.w+ad.w; pv.w = __expf(x>0.f?x:0.2f*x);
    *(float4*)(pw_po + (size_t)p*4) = pv;
  } else if(i < EPO+EADJ){
    int e = i-EPO;
    int s = src_adj[e];
    int d = dst_adj[e];
    int p = atomicAdd(&cur[NI+d],1);
    csr_adj[p] = s;
    float4 as = *(const float4*)(a_s_adj + (size_t)s*4);
    float4 ad = *(const float4*)(a_d_adj + (size_t)d*4);
    float4 pv;
    float x;
    x = as.x+ad.x; pv.x = __expf(x>0.f?x:0.2f*x);
    x = as.y+ad.y; pv.y = __expf(x>0.f?x:0.2f*x);
    x = as.z+ad.z; pv.z = __expf(x>0.f?x:0.2f*x);
    x = as.w+ad.w; pv.w = __expf(x>0.f?x:0.2f*x);
    *(float4*)(pw_adj + (size_t)p*4) = pv;
  }
}

// ---------------- K6: weighted-sum aggregation, 4-way independent edge chains ----------------
__device__ __forceinline__ void agg_rel(
    int beg, int n, int lane,
    const int* __restrict__ csr, const float* __restrict__ pw,
    const u16* __restrict__ emat, u16* __restrict__ aggrow)
{
  float l0=0,l1=0,l2=0,l3=0;
  float c0=0,c1=0,c2=0,c3=0;
  for(int base=0;base<n;base+=64){
    int m = n-base; if(m>64) m=64;
    int sv_ = (lane<m) ? csr[beg+base+lane] : 0;
    int t2=0;
    for(; t2+3<m; t2+=4){
      int s0 = __shfl(sv_, t2,   64);
      int s1 = __shfl(sv_, t2+1, 64);
      int s2 = __shfl(sv_, t2+2, 64);
      int s3 = __shfl(sv_, t2+3, 64);
      float4 p0 = *(const float4*)(pw + (size_t)(beg+base+t2  )*4);
      float4 p1 = *(const float4*)(pw + (size_t)(beg+base+t2+1)*4);
      float4 p2 = *(const float4*)(pw + (size_t)(beg+base+t2+2)*4);
      float4 p3 = *(const float4*)(pw + (size_t)(beg+base+t2+3)*4);
      float e0 = bf2f(emat[(size_t)s0*64+lane]);
      float e1 = bf2f(emat[(size_t)s1*64+lane]);
      float e2 = bf2f(emat[(size_t)s2*64+lane]);
      float e3 = bf2f(emat[(size_t)s3*64+lane]);
      c0 += p0.x*e0; c1 += p0.y*e0; c2 += p0.z*e0; c3 += p0.w*e0;
      l0 += p0.x;    l1 += p0.y;    l2 += p0.z;    l3 += p0.w;
      c0 += p1.x*e1; c1 += p1.y*e1; c2 += p1.z*e1; c3 += p1.w*e1;
      l0 += p1.x;    l1 += p1.y;    l2 += p1.z;    l3 += p1.w;
      c0 += p2.x*e2; c1 += p2.y*e2; c2 += p2.z*e2; c3 += p2.w*e2;
      l0 += p2.x;    l1 += p2.y;    l2 += p2.z;    l3 += p2.w;
      c0 += p3.x*e3; c1 += p3.y*e3; c2 += p3.z*e3; c3 += p3.w*e3;
      l0 += p3.x;    l1 += p3.y;    l2 += p3.z;    l3 += p3.w;
    }
    for(; t2<m; t2++){
      int s0 = __shfl(sv_, t2, 64);
      float4 p0 = *(const float4*)(pw + (size_t)(beg+base+t2)*4);
      float e0 = bf2f(emat[(size_t)s0*64+lane]);
      c0 += p0.x*e0; c1 += p0.y*e0; c2 += p0.z*e0; c3 += p0.w*e0;
      l0 += p0.x;    l1 += p0.y;    l2 += p0.z;    l3 += p0.w;
    }
  }
  aggrow[lane]       = f2bf(n>0 ? c0/l0 : 0.f);
  aggrow[64+lane]    = f2bf(n>0 ? c1/l1 : 0.f);
  aggrow[128+lane]   = f2bf(n>0 ? c2/l2 : 0.f);
  aggrow[192+lane]   = f2bf(n>0 ? c3/l3 : 0.f);
}

__global__ __launch_bounds__(512) void k6_agg(
    const int* __restrict__ off, const int* __restrict__ cnt,
    const int* __restrict__ csr_po, const int* __restrict__ csr_adj,
    const float* __restrict__ pw_po, const float* __restrict__ pw_adj,
    const u16* __restrict__ e_lane, const u16* __restrict__ e_int,
    u16* __restrict__ agg)
{
  int wave=threadIdx.x>>6, lane=threadIdx.x&63;
  int d = blockIdx.x*4 + (wave&3);
  if(d>=NI) return;
  if(wave < 4)
    agg_rel(off[d],    cnt[d],    lane, csr_po,  pw_po,  e_lane, agg + (size_t)d*512);
  else
    agg_rel(off[NI+d], cnt[NI+d], lane, csr_adj, pw_adj, e_int,  agg + (size_t)d*512 + 256);
}

// ---------------- K8 v2: fragment-direct head GEMMs (wave=head, no staging/barriers)
//                  + GRU GEMM + gates + output heads ----------------
__global__ __launch_bounds__(256) void k8_fused(
    const u16* __restrict__ agg, const uint4* __restrict__ WheadF,
    const float* __restrict__ bias_comb,
    const uint4* __restrict__ B2F, const float* __restrict__ bias2,
    const float* __restrict__ h0,
    const float* __restrict__ Wpi, const float* __restrict__ bpi,
    const float* __restrict__ Wv, const float* __restrict__ bvp,
    float* __restrict__ out)
{
  __shared__ u16 interT[64][264];
  int t=threadIdx.x, w=t>>6, lane=t&63;
  int r = lane&15, q = lane>>4;
  int row0 = blockIdx.x*64;
  int h = w;   // wave w owns head w

  // ---- phase 1: head-h GEMM, fragment-direct, 64 rows x 64 cols ----
  const uint4* BF = WheadF + (size_t)h*16*64;   // [kt][ct][lane]
#pragma unroll
  for(int rt=0; rt<4; rt++){
    int row = row0 + rt*16 + r;
    int arc = row < NI ? row : NI-1;
    const u16* arow_p = agg + (size_t)arc*512;
    bf16x8 af[4];
#pragma unroll
    for(int kt=0; kt<4; kt++){
      int colbase = (kt<2) ? (h*64 + kt*32) : (256 + h*64 + (kt-2)*32);
      af[kt] = *(const bf16x8*)(arow_p + colbase + q*8);
    }
#pragma unroll
    for(int ct=0; ct<4; ct++){
      f32x4 facc = {0,0,0,0};
#pragma unroll
      for(int kt=0; kt<4; kt++){
        uint4 bu = BF[(kt*4 + ct)*64 + lane];
        bf16x8 bfr; *(uint4*)&bfr = bu;
        facc = __builtin_amdgcn_mfma_f32_16x16x32_bf16(af[kt], bfr, facc, 0,0,0);
      }
      int col = h*64 + ct*16 + r;
      float bcol = bias_comb[col];
#pragma unroll
      for(int rr=0; rr<4; rr++)
        interT[rt*16 + q*4 + rr][col] = f2bf(fmaxf(facc[rr]+bcol, 0.f));
    }
  }
  __syncthreads();

  // ---- phase 2: GRU GEMM (A-fragments from LDS) + gates + output heads ----
  int arowl = w*16 + r;
  int arow  = row0 + arowl;
  int arc = arow < NI ? arow : NI-1;
  const float* h0r = h0 + (size_t)arc*64 + q*8;
  f32x4 acc[16];
#pragma unroll
  for(int i=0;i<16;i++) acc[i] = (f32x4){0,0,0,0};
#pragma unroll
  for(int ks=0; ks<10; ks++){
    bf16x8 af;
    if(ks < 8){
      af = *(const bf16x8*)&interT[arowl][ks*32 + q*8];
    } else {
      const float* hp = h0r + (ks-8)*32;
      float4 f0 = *(const float4*)(hp);
      float4 f1 = *(const float4*)(hp+4);
      uint4 P;
      P.x = pack2(f0.x,f0.y); P.y = pack2(f0.z,f0.w);
      P.z = pack2(f1.x,f1.y); P.w = pack2(f1.z,f1.w);
      *(uint4*)&af = P;
    }
    const uint4* bp = B2F + ks*1024 + lane;
#pragma unroll
    for(int tt=0;tt<16;tt++){
      uint4 bu = bp[tt*64];
      bf16x8 bfr; *(uint4*)&bfr = bu;
      acc[tt] = __builtin_amdgcn_mfma_f32_16x16x32_bf16(af, bfr, acc[tt], 0,0,0);
    }
  }
  float pk[4][8];
  float pv[4];
#pragma unroll
  for(int rr=0;rr<4;rr++){
    pv[rr]=0.f;
#pragma unroll
    for(int j=0;j<8;j++) pk[rr][j]=0.f;
  }
  int rbase = row0 + w*16 + q*4;
#pragma unroll
  for(int t2=0;t2<4;t2++){
    int c = t2*16 + r;
    float b0 = bias2[c], b1 = bias2[64+c], b2 = bias2[128+c], b3 = bias2[192+c];
    float wp[8];
#pragma unroll
    for(int j=0;j<8;j++) wp[j] = Wpi[c*8+j];
    float wv = Wv[c];
#pragma unroll
    for(int rr=0;rr<4;rr++){
      int row = rbase + rr;
      float g0 = acc[t2][rr]    + b0;
      float g1 = acc[t2+4][rr]  + b1;
      float g2 = acc[t2+8][rr]  + b2;
      float g3 = acc[t2+12][rr] + b3;
      float h0v = (row < NI) ? h0[(size_t)row*64 + c] : 0.f;
      float rg = 1.f/(1.f+__expf(-g0));
      float zg = 1.f/(1.f+__expf(-g1));
      float e2 = __expf(2.f*(g2 + rg*g3));
      float ng = 1.f - 2.f/(e2+1.f);
      float hh = (1.f-zg)*ng + zg*h0v;
      if(row < NI) out[450000 + (size_t)row*64 + c] = hh;
#pragma unroll
      for(int j=0;j<8;j++) pk[rr][j] += hh*wp[j];
      pv[rr] += hh*wv;
    }
  }
#pragma unroll
  for(int o=1;o<16;o<<=1){
#pragma unroll
    for(int rr=0;rr<4;rr++){
#pragma unroll
      for(int j=0;j<8;j++) pk[rr][j] += __shfl_xor(pk[rr][j], o, 64);
      pv[rr] += __shfl_xor(pv[rr], o, 64);
    }
  }
  if(r==0){
#pragma unroll
    for(int rr=0;rr<4;rr++){
      int row = rbase + rr;
      if(row < NI){
#pragma unroll
        for(int j=0;j<8;j++) out[(size_t)row*8 + j] = pk[rr][j] + bpi[j];
        out[400000 + row] = pv[rr] + bvp[0];
      }
    }
  }
}

extern "C" void kernel_launch(void* const* d_in, const int* in_sizes, int n_in,
                              void* d_out, int out_size, void* d_ws, size_t ws_size,
                              hipStream_t stream) {
  const float* x_int      = (const float*)d_in[0];
  const float* x_lane     = (const float*)d_in[1];
  const float* h0         = (const float*)d_in[2];
  const float* enc_int_W  = (const float*)d_in[3];
  const float* enc_int_b  = (const float*)d_in[4];
  const float* enc_lane_W = (const float*)d_in[5];
  const float* enc_lane_b = (const float*)d_in[6];
  const float* Wsrc_po    = (const float*)d_in[7];
  const float* Wdst_po    = (const float*)d_in[8];
  const float* att_src_po = (const float*)d_in[9];
  const float* att_dst_po = (const float*)d_in[10];
  const float* bias_po    = (const float*)d_in[11];
  const float* Wsrc_adj   = (const float*)d_in[12];
  const float* Wdst_adj   = (const float*)d_in[13];
  const float* att_src_adj= (const float*)d_in[14];
  const float* att_dst_adj= (const float*)d_in[15];
  const float* bias_adj   = (const float*)d_in[16];
  const float* gru_W_ih   = (const float*)d_in[17];
  const float* gru_W_hh   = (const float*)d_in[18];
  const float* gru_b_ih   = (const float*)d_in[19];
  const float* gru_b_hh   = (const float*)d_in[20];
  const float* W_pi       = (const float*)d_in[21];
  const float* b_pi       = (const float*)d_in[22];
  const float* W_v        = (const float*)d_in[23];
  const float* b_v        = (const float*)d_in[24];
  const int* src_po  = (const int*)d_in[25];
  const int* dst_po  = (const int*)d_in[26];
  const int* src_adj = (const int*)d_in[27];
  const int* dst_adj = (const int*)d_in[28];
  float* out = (float*)d_out;

  char* w = (char*)d_ws;
  size_t ofs = 0;
  auto alloc = [&](size_t bytes)->char*{
    char* p = w + ofs;
    ofs = (ofs + bytes + 255) & ~(size_t)255;
    return p;
  };
  u16*  e_lane   = (u16*)alloc((size_t)NL*64*2);
  u16*  e_int    = (u16*)alloc((size_t)NI*64*2);
  float* a_s_po  = (float*)alloc((size_t)NL*4*4);
  float* a_d_po  = (float*)alloc((size_t)NI*4*4);
  float* a_s_adj = (float*)alloc((size_t)NI*4*4);
  float* a_d_adj = (float*)alloc((size_t)NI*4*4);
  int*  cnt      = (int*)alloc((size_t)2*NI*4);
  int*  offA     = (int*)alloc((size_t)2*NI*4);
  int*  cur      = (int*)alloc((size_t)2*NI*4);
  int*  csr_po   = (int*)alloc((size_t)EPO*4);
  int*  csr_adj  = (int*)alloc((size_t)EADJ*4);
  float* pw_po   = (float*)alloc((size_t)EPO*4*4);
  float* pw_adj  = (float*)alloc((size_t)EADJ*4*4);
  int*  bsum     = (int*)alloc(2*64*4);
  u16*  agg      = (u16*)alloc((size_t)NI*512*2);
  u16*  WheadF   = (u16*)alloc(4*4*4*64*8*2);
  u16*  B2F      = (u16*)alloc(10*16*64*8*2);
  float* v4      = (float*)alloc(4*256*4);
  float* bias_comb = (float*)alloc(256*4);
  float* bias2   = (float*)alloc(256*4);
  (void)ws_size; (void)n_in; (void)in_sizes; (void)out_size;

  k0_prep<<<256, 256, 0, stream>>>(
      Wsrc_po, att_src_po, Wdst_po, att_dst_po,
      Wsrc_adj, att_src_adj, Wdst_adj, att_dst_adj,
      gru_W_ih, gru_W_hh, bias_po, bias_adj, gru_b_ih, gru_b_hh,
      v4, WheadF, B2F, bias_comb, bias2, cnt);
  k_enc<<<NLB+NIB+NHB, 256, 0, stream>>>(
      x_lane, enc_lane_W, enc_lane_b,
      x_int, enc_int_W, enc_int_b,
      v4 + 0, v4 + 256, v4 + 512, v4 + 768,
      e_lane, a_s_po, e_int, a_d_po, a_s_adj, a_d_adj,
      dst_po, dst_adj, cnt);
  k4a_scan<<<dim3(49,2), 1024, 0, stream>>>(cnt, offA, bsum);
  k4b_scanb<<<1, 128, 0, stream>>>(bsum);
  k4c_add<<<dim3(49,2), 1024, 0, stream>>>(offA, cur, bsum);
  k5_scatter<<<(EPO+EADJ+255)/256, 256, 0, stream>>>(src_po, dst_po, src_adj, dst_adj,
      a_s_po, a_d_po, a_s_adj, a_d_adj,
      cur, csr_po, csr_adj, pw_po, pw_adj);
  k6_agg<<<(NI+3)/4, 512, 0, stream>>>(offA, cnt, csr_po, csr_adj,
      pw_po, pw_adj, e_lane, e_int, agg);
  k8_fused<<<(NI+63)/64, 256, 0, stream>>>(agg, (const uint4*)WheadF, bias_comb,
      (const uint4*)B2F, bias2, h0, W_pi, b_pi, W_v, b_v, out);
}

// Round 14
// 357.920 us; speedup vs baseline: 1.1308x; 1.1308x over previous
//
#include <hip/hip_runtime.h>

#define NI 50000
#define NL 400000
#define EPO 400000
#define EADJ 200000

// encoder tiling
#define K1_ITER 8
#define K2_ITER 4
#define K1_ROWS (32*K1_ITER)   // 256 rows/block
#define K2_ROWS (32*K2_ITER)   // 128 rows/block
#define NLB ((NL + K1_ROWS - 1)/K1_ROWS)   // 1563
#define NIB ((NI + K2_ROWS - 1)/K2_ROWS)   // 391
#define NHB ((EPO + EADJ + 255)/256)       // 2344 histogram blocks

typedef unsigned int u32;
typedef unsigned short u16;
typedef short bf16x8 __attribute__((ext_vector_type(8)));
typedef float f32x4 __attribute__((ext_vector_type(4)));

__device__ __forceinline__ float bf2f(u16 h){ return __uint_as_float(((u32)h)<<16); }
__device__ __forceinline__ u16 f2bf(float f){
  u32 u = __float_as_uint(f);
  u += 0x7FFFu + ((u>>16)&1u);
  return (u16)(u>>16);
}
__device__ __forceinline__ u32 pack2(float a, float b){
  return (u32)f2bf(a) | ((u32)f2bf(b)<<16);
}

// GRU combined weight value: maps [inter(256) | h0(64)] -> [r_sum, z_sum, i_n, h_n]
__device__ __forceinline__ float b2_val(
    const float* __restrict__ W_ih, const float* __restrict__ W_hh, int m, int k)
{
  if(k < 256){ return (m<192) ? W_ih[m*256+k] : 0.f; }
  int kk = k-256;
  if(m<128) return W_hh[m*64+kk];
  if(m>=192) return W_hh[(m-64)*64+kk];
  return 0.f;
}

// ---------------- K0: weight prep + cnt zeroing (R12 layout: WheadT rows) ----------------
__global__ __launch_bounds__(256) void k0_prep(
    const float* __restrict__ Wsrc_po, const float* __restrict__ att_src_po,
    const float* __restrict__ Wdst_po, const float* __restrict__ att_dst_po,
    const float* __restrict__ Wsrc_adj, const float* __restrict__ att_src_adj,
    const float* __restrict__ Wdst_adj, const float* __restrict__ att_dst_adj,
    const float* __restrict__ W_ih, const float* __restrict__ W_hh,
    const float* __restrict__ bias_po, const float* __restrict__ bias_adj,
    const float* __restrict__ b_ih, const float* __restrict__ b_hh,
    float* __restrict__ v4, u16* __restrict__ WheadT, u16* __restrict__ B2F,
    float* __restrict__ bias_comb, float* __restrict__ bias2,
    int* __restrict__ cnt)
{
  const int T0 = 1024, T1 = 4*64*128, T2 = 10*16*64*8;
  const int TC = 2*NI;
  int total = T0 + T1 + T2 + 256 + 256 + TC;
  for(int t = blockIdx.x*256 + threadIdx.x; t < total; t += gridDim.x*256){
    if(t < T0){
      int which = t>>8, hc = t&255, h = hc>>6, c = hc&63;
      const float *W, *att;
      if(which==0){ W=Wsrc_po;  att=att_src_po; }
      else if(which==1){ W=Wdst_po;  att=att_dst_po; }
      else if(which==2){ W=Wsrc_adj; att=att_src_adj; }
      else { W=Wdst_adj; att=att_dst_adj; }
      float s=0.f;
      for(int j=0;j<64;j++) s += W[c*256 + h*64 + j]*att[h*64+j];
      v4[which*256 + hc] = s;
    } else if(t < T0 + T1){
      int i = t - T0; int h = i>>13, rem = i&8191, m = rem>>7, k = rem&127;
      float val = (k<64) ? Wsrc_po[k*256 + h*64 + m]
                         : Wsrc_adj[(k-64)*256 + h*64 + m];
      WheadT[i] = f2bf(val);
    } else if(t < T0 + T1 + T2){
      int i = t - (T0+T1);
      int j = i&7;
      int u4 = i>>3;
      int kstep = u4>>10, rem = u4&1023, tile = rem>>6, lane = rem&63;
      int col = tile*16 + (lane&15);
      int k = kstep*32 + (lane>>4)*8 + j;
      B2F[i] = f2bf(b2_val(W_ih, W_hh, col, k));
    } else if(t < T0 + T1 + T2 + 256){
      int m = t - (T0+T1+T2);
      bias_comb[m] = bias_po[m] + bias_adj[m];
    } else if(t < T0 + T1 + T2 + 512){
      int m = t - (T0+T1+T2+256);
      float v;
      if(m<128) v = b_ih[m] + b_hh[m];
      else if(m<192) v = b_ih[m];
      else v = b_hh[m-64];
      bias2[m] = v;
    } else {
      cnt[t - (T0+T1+T2+512)] = 0;
    }
  }
}

// ---------------- K_ENC: fused lane+int encoders + edge histogram ----------------
__global__ __launch_bounds__(256) void k_enc(
    const float* __restrict__ x_lane, const float* __restrict__ Wl, const float* __restrict__ bl,
    const float* __restrict__ x_int,  const float* __restrict__ Wi, const float* __restrict__ bi,
    const float* __restrict__ v_sp, const float* __restrict__ v_dp,
    const float* __restrict__ v_sa, const float* __restrict__ v_da,
    u16* __restrict__ e_lane, float* __restrict__ a_s_po,
    u16* __restrict__ e_int, float* __restrict__ a_dp, float* __restrict__ a_sa,
    float* __restrict__ a_da,
    const int* __restrict__ dst_po, const int* __restrict__ dst_adj,
    int* __restrict__ cnt)
{
  int t = threadIdx.x;
  int wv = t>>6, l = t&63;
  int g = l&7, m = l>>3;
  int blk = blockIdx.x;
  if(blk < NLB){
    float wreg[12][8], breg[8];
#pragma unroll
    for(int k=0;k<12;k++){
      float4 w0 = *(const float4*)(Wl + k*64 + g*8);
      float4 w1 = *(const float4*)(Wl + k*64 + g*8 + 4);
      wreg[k][0]=w0.x; wreg[k][1]=w0.y; wreg[k][2]=w0.z; wreg[k][3]=w0.w;
      wreg[k][4]=w1.x; wreg[k][5]=w1.y; wreg[k][6]=w1.z; wreg[k][7]=w1.w;
    }
    {
      float4 b0 = *(const float4*)(bl + g*8);
      float4 b1 = *(const float4*)(bl + g*8 + 4);
      breg[0]=b0.x; breg[1]=b0.y; breg[2]=b0.z; breg[3]=b0.w;
      breg[4]=b1.x; breg[5]=b1.y; breg[6]=b1.z; breg[7]=b1.w;
    }
    int rowbase = blk*K1_ROWS + wv*(8*K1_ITER) + m;
    float4 Aa={0,0,0,0}, Ab={0,0,0,0}, Ac={0,0,0,0};
    float4 Ba={0,0,0,0}, Bb={0,0,0,0}, Bc={0,0,0,0};
    if(rowbase < NL){
      const float4* xp = (const float4*)(x_lane + (size_t)rowbase*12);
      Aa = xp[0]; Ab = xp[1]; Ac = xp[2];
    }
    if(rowbase+8 < NL){
      const float4* xp = (const float4*)(x_lane + (size_t)(rowbase+8)*12);
      Ba = xp[0]; Bb = xp[1]; Bc = xp[2];
    }
#pragma unroll
    for(int it=0; it<K1_ITER; it++){
      int row = rowbase + it*8;
      float4 Ca={0,0,0,0}, Cb={0,0,0,0}, Cc={0,0,0,0};
      if(it+2 < K1_ITER && row+16 < NL){
        const float4* xp = (const float4*)(x_lane + (size_t)(row+16)*12);
        Ca = xp[0]; Cb = xp[1]; Cc = xp[2];
      }
      float xv[12];
      xv[0]=Aa.x; xv[1]=Aa.y; xv[2]=Aa.z; xv[3]=Aa.w;
      xv[4]=Ab.x; xv[5]=Ab.y; xv[6]=Ab.z; xv[7]=Ab.w;
      xv[8]=Ac.x; xv[9]=Ac.y; xv[10]=Ac.z; xv[11]=Ac.w;
      float acc[8];
#pragma unroll
      for(int j=0;j<8;j++) acc[j]=breg[j];
#pragma unroll
      for(int k=0;k<12;k++){
        float xk = xv[k];
#pragma unroll
        for(int j=0;j<8;j++) acc[j] += xk*wreg[k][j];
      }
      float e[8];
#pragma unroll
      for(int j=0;j<8;j++) e[j] = fmaxf(acc[j], 0.f);
      float as[4];
#pragma unroll
      for(int h=0;h<4;h++){
        float4 v0 = *(const float4*)(v_sp + h*64 + g*8);
        float4 v1 = *(const float4*)(v_sp + h*64 + g*8 + 4);
        as[h] = e[0]*v0.x + e[1]*v0.y + e[2]*v0.z + e[3]*v0.w
              + e[4]*v1.x + e[5]*v1.y + e[6]*v1.z + e[7]*v1.w;
      }
#pragma unroll
      for(int o=1;o<8;o<<=1){
#pragma unroll
        for(int h=0;h<4;h++) as[h] += __shfl_xor(as[h], o, 64);
      }
      if(row < NL){
        uint4 P;
        P.x = pack2(e[0],e[1]); P.y = pack2(e[2],e[3]);
        P.z = pack2(e[4],e[5]); P.w = pack2(e[6],e[7]);
        ((uint4*)e_lane)[(size_t)row*8 + g] = P;
        if(g==0){
          float4 A; A.x=as[0]; A.y=as[1]; A.z=as[2]; A.w=as[3];
          *(float4*)(a_s_po + (size_t)row*4) = A;
        }
      }
      Aa=Ba; Ab=Bb; Ac=Bc;
      Ba=Ca; Bb=Cb; Bc=Cc;
    }
  } else if(blk < NLB + NIB){
    int b2 = blk - NLB;
    float breg[8];
    {
      float4 b0 = *(const float4*)(bi + g*8);
      float4 b1 = *(const float4*)(bi + g*8 + 4);
      breg[0]=b0.x; breg[1]=b0.y; breg[2]=b0.z; breg[3]=b0.w;
      breg[4]=b1.x; breg[5]=b1.y; breg[6]=b1.z; breg[7]=b1.w;
    }
    int rowbase = b2*K2_ROWS + wv*(8*K2_ITER) + m;
#pragma unroll
    for(int it=0; it<K2_ITER; it++){
      int row = rowbase + it*8;
      float xv[16];
      if(row < NI){
        const float4* xp = (const float4*)(x_int + (size_t)row*16);
#pragma unroll
        for(int q=0;q<4;q++){
          float4 xq = xp[q];
          xv[q*4]=xq.x; xv[q*4+1]=xq.y; xv[q*4+2]=xq.z; xv[q*4+3]=xq.w;
        }
      } else {
#pragma unroll
        for(int k=0;k<16;k++) xv[k]=0.f;
      }
      float acc[8];
#pragma unroll
      for(int j=0;j<8;j++) acc[j]=breg[j];
#pragma unroll
      for(int k=0;k<16;k++){
        float4 w0 = *(const float4*)(Wi + k*64 + g*8);
        float4 w1 = *(const float4*)(Wi + k*64 + g*8 + 4);
        float xk = xv[k];
        acc[0] += xk*w0.x; acc[1] += xk*w0.y; acc[2] += xk*w0.z; acc[3] += xk*w0.w;
        acc[4] += xk*w1.x; acc[5] += xk*w1.y; acc[6] += xk*w1.z; acc[7] += xk*w1.w;
      }
      float e[8];
#pragma unroll
      for(int j=0;j<8;j++) e[j] = fmaxf(acc[j], 0.f);
      float ad[4], sa[4], da[4];
#pragma unroll
      for(int h=0;h<4;h++){
        float4 v0, v1;
        v0 = *(const float4*)(v_dp + h*64 + g*8); v1 = *(const float4*)(v_dp + h*64 + g*8 + 4);
        ad[h] = e[0]*v0.x + e[1]*v0.y + e[2]*v0.z + e[3]*v0.w
              + e[4]*v1.x + e[5]*v1.y + e[6]*v1.z + e[7]*v1.w;
        v0 = *(const float4*)(v_sa + h*64 + g*8); v1 = *(const float4*)(v_sa + h*64 + g*8 + 4);
        sa[h] = e[0]*v0.x + e[1]*v0.y + e[2]*v0.z + e[3]*v0.w
              + e[4]*v1.x + e[5]*v1.y + e[6]*v1.z + e[7]*v1.w;
        v0 = *(const float4*)(v_da + h*64 + g*8); v1 = *(const float4*)(v_da + h*64 + g*8 + 4);
        da[h] = e[0]*v0.x + e[1]*v0.y + e[2]*v0.z + e[3]*v0.w
              + e[4]*v1.x + e[5]*v1.y + e[6]*v1.z + e[7]*v1.w;
      }
#pragma unroll
      for(int o=1;o<8;o<<=1){
#pragma unroll
        for(int h=0;h<4;h++){
          ad[h] += __shfl_xor(ad[h], o, 64);
          sa[h] += __shfl_xor(sa[h], o, 64);
          da[h] += __shfl_xor(da[h], o, 64);
        }
      }
      if(row < NI){
        uint4 P;
        P.x = pack2(e[0],e[1]); P.y = pack2(e[2],e[3]);
        P.z = pack2(e[4],e[5]); P.w = pack2(e[6],e[7]);
        ((uint4*)e_int)[(size_t)row*8 + g] = P;
        if(g==0){
          float4 A;
          A.x=ad[0]; A.y=ad[1]; A.z=ad[2]; A.w=ad[3]; *(float4*)(a_dp + (size_t)row*4) = A;
          A.x=sa[0]; A.y=sa[1]; A.z=sa[2]; A.w=sa[3]; *(float4*)(a_sa + (size_t)row*4) = A;
          A.x=da[0]; A.y=da[1]; A.z=da[2]; A.w=da[3]; *(float4*)(a_da + (size_t)row*4) = A;
        }
      }
    }
  } else {
    int i = (blk - NLB - NIB)*256 + t;
    if(i < EPO) atomicAdd(&cnt[dst_po[i]], 1);
    else if(i < EPO+EADJ) atomicAdd(&cnt[NI + dst_adj[i-EPO]], 1);
  }
}

// ---------------- K4: parallel 3-phase scan ----------------
__global__ __launch_bounds__(1024) void k4a_scan(
    const int* __restrict__ cnt, int* __restrict__ offA, int* __restrict__ bsum)
{
  __shared__ int s[1024];
  int y = blockIdx.y;
  int i = blockIdx.x*1024 + threadIdx.x;
  int v = (i<NI) ? cnt[y*NI+i] : 0;
  s[threadIdx.x]=v;
  __syncthreads();
  for(int o=1;o<1024;o<<=1){
    int t = (threadIdx.x>=o) ? s[threadIdx.x-o] : 0;
    __syncthreads();
    s[threadIdx.x] += t;
    __syncthreads();
  }
  if(i<NI) offA[y*NI+i] = s[threadIdx.x]-v;
  if(threadIdx.x==1023) bsum[y*64+blockIdx.x] = s[1023];
}

__global__ __launch_bounds__(128) void k4b_scanb(int* __restrict__ bsum)
{
  int y = threadIdx.x>>6, lane = threadIdx.x&63;
  int v = (lane<49) ? bsum[y*64+lane] : 0;
  int orig = v;
#pragma unroll
  for(int o=1;o<64;o<<=1){
    int t = __shfl_up(v,o,64);
    if(lane>=o) v += t;
  }
  if(lane<49) bsum[y*64+lane] = v-orig;
}

__global__ __launch_bounds__(1024) void k4c_add(
    int* __restrict__ offA, int* __restrict__ cur, const int* __restrict__ bsum)
{
  int y = blockIdx.y;
  int i = blockIdx.x*1024 + threadIdx.x;
  if(i<NI){
    int o = offA[y*NI+i] + bsum[y*64+blockIdx.x];
    offA[y*NI+i]=o;
    cur[y*NI+i]=o;
  }
}

// ---------------- K5: scatter src + per-edge softmax numerator weights ----------------
__global__ __launch_bounds__(256) void k5_scatter(
    const int* __restrict__ src_po, const int* __restrict__ dst_po,
    const int* __restrict__ src_adj, const int* __restrict__ dst_adj,
    const float* __restrict__ a_s_po, const float* __restrict__ a_d_po,
    const float* __restrict__ a_s_adj, const float* __restrict__ a_d_adj,
    int* __restrict__ cur, int* __restrict__ csr_po, int* __restrict__ csr_adj,
    float* __restrict__ pw_po, float* __restrict__ pw_adj)
{
  int i = blockIdx.x*256 + threadIdx.x;
  if(i < EPO){
    int s = src_po[i];
    int d = dst_po[i];
    int p = atomicAdd(&cur[d],1);
    csr_po[p] = s;
    float4 as = *(const float4*)(a_s_po + (size_t)s*4);
    float4 ad = *(const float4*)(a_d_po + (size_t)d*4);
    float4 pv;
    float x;
    x = as.x+ad.x; pv.x = __expf(x>0.f?x:0.2f*x);
    x = as.y+ad.y; pv.y = __expf(x>0.f?x:0.2f*x);
    x = as.z+ad.z; pv.z = __expf(x>0.f?x:0.2f*x);
    x = as.w+ad.w; pv.w = __expf(x>0.f?x:0.2f*x);
    *(float4*)(pw_po + (size_t)p*4) = pv;
  } else if(i < EPO+EADJ){
    int e = i-EPO;
    int s = src_adj[e];
    int d = dst_adj[e];
    int p = atomicAdd(&cur[NI+d],1);
    csr_adj[p] = s;
    float4 as = *(const float4*)(a_s_adj + (size_t)s*4);
    float4 ad = *(const float4*)(a_d_adj + (size_t)d*4);
    float4 pv;
    float x;
    x = as.x+ad.x; pv.x = __expf(x>0.f?x:0.2f*x);
    x = as.y+ad.y; pv.y = __expf(x>0.f?x:0.2f*x);
    x = as.z+ad.z; pv.z = __expf(x>0.f?x:0.2f*x);
    x = as.w+ad.w; pv.w = __expf(x>0.f?x:0.2f*x);
    *(float4*)(pw_adj + (size_t)p*4) = pv;
  }
}

// ---------------- K6: weighted-sum aggregation, 4-way independent edge chains ----------------
__device__ __forceinline__ void agg_rel(
    int beg, int n, int lane,
    const int* __restrict__ csr, const float* __restrict__ pw,
    const u16* __restrict__ emat, u16* __restrict__ aggrow)
{
  float l0=0,l1=0,l2=0,l3=0;
  float c0=0,c1=0,c2=0,c3=0;
  for(int base=0;base<n;base+=64){
    int m = n-base; if(m>64) m=64;
    int sv_ = (lane<m) ? csr[beg+base+lane] : 0;
    int t2=0;
    for(; t2+3<m; t2+=4){
      int s0 = __shfl(sv_, t2,   64);
      int s1 = __shfl(sv_, t2+1, 64);
      int s2 = __shfl(sv_, t2+2, 64);
      int s3 = __shfl(sv_, t2+3, 64);
      float4 p0 = *(const float4*)(pw + (size_t)(beg+base+t2  )*4);
      float4 p1 = *(const float4*)(pw + (size_t)(beg+base+t2+1)*4);
      float4 p2 = *(const float4*)(pw + (size_t)(beg+base+t2+2)*4);
      float4 p3 = *(const float4*)(pw + (size_t)(beg+base+t2+3)*4);
      float e0 = bf2f(emat[(size_t)s0*64+lane]);
      float e1 = bf2f(emat[(size_t)s1*64+lane]);
      float e2 = bf2f(emat[(size_t)s2*64+lane]);
      float e3 = bf2f(emat[(size_t)s3*64+lane]);
      c0 += p0.x*e0; c1 += p0.y*e0; c2 += p0.z*e0; c3 += p0.w*e0;
      l0 += p0.x;    l1 += p0.y;    l2 += p0.z;    l3 += p0.w;
      c0 += p1.x*e1; c1 += p1.y*e1; c2 += p1.z*e1; c3 += p1.w*e1;
      l0 += p1.x;    l1 += p1.y;    l2 += p1.z;    l3 += p1.w;
      c0 += p2.x*e2; c1 += p2.y*e2; c2 += p2.z*e2; c3 += p2.w*e2;
      l0 += p2.x;    l1 += p2.y;    l2 += p2.z;    l3 += p2.w;
      c0 += p3.x*e3; c1 += p3.y*e3; c2 += p3.z*e3; c3 += p3.w*e3;
      l0 += p3.x;    l1 += p3.y;    l2 += p3.z;    l3 += p3.w;
    }
    for(; t2<m; t2++){
      int s0 = __shfl(sv_, t2, 64);
      float4 p0 = *(const float4*)(pw + (size_t)(beg+base+t2)*4);
      float e0 = bf2f(emat[(size_t)s0*64+lane]);
      c0 += p0.x*e0; c1 += p0.y*e0; c2 += p0.z*e0; c3 += p0.w*e0;
      l0 += p0.x;    l1 += p0.y;    l2 += p0.z;    l3 += p0.w;
    }
  }
  aggrow[lane]       = f2bf(n>0 ? c0/l0 : 0.f);
  aggrow[64+lane]    = f2bf(n>0 ? c1/l1 : 0.f);
  aggrow[128+lane]   = f2bf(n>0 ? c2/l2 : 0.f);
  aggrow[192+lane]   = f2bf(n>0 ? c3/l3 : 0.f);
}

__global__ __launch_bounds__(512) void k6_agg(
    const int* __restrict__ off, const int* __restrict__ cnt,
    const int* __restrict__ csr_po, const int* __restrict__ csr_adj,
    const float* __restrict__ pw_po, const float* __restrict__ pw_adj,
    const u16* __restrict__ e_lane, const u16* __restrict__ e_int,
    u16* __restrict__ agg)
{
  int wave=threadIdx.x>>6, lane=threadIdx.x&63;
  int d = blockIdx.x*4 + (wave&3);
  if(d>=NI) return;
  if(wave < 4)
    agg_rel(off[d],    cnt[d],    lane, csr_po,  pw_po,  e_lane, agg + (size_t)d*512);
  else
    agg_rel(off[NI+d], cnt[NI+d], lane, csr_adj, pw_adj, e_int,  agg + (size_t)d*512 + 256);
}

// ---------------- K8 (R12 staged version): head GEMMs via LDS + GRU GEMM + gates ----------------
__global__ __launch_bounds__(256) void k8_fused(
    const u16* __restrict__ agg, const u16* __restrict__ WheadT,
    const float* __restrict__ bias_comb,
    const uint4* __restrict__ B2F, const float* __restrict__ bias2,
    const float* __restrict__ h0,
    const float* __restrict__ Wpi, const float* __restrict__ bpi,
    const float* __restrict__ Wv, const float* __restrict__ bvp,
    float* __restrict__ out)
{
  __shared__ u16 As[64][136];
  __shared__ u16 Bs[64][136];
  __shared__ u16 interT[64][264];
  int t=threadIdx.x, w=t>>6, lane=t&63;
  int r = lane&15, q = lane>>4;
  int row0 = blockIdx.x*64;

  // ---- phase 1: 4 per-head GEMMs -> interT (LDS) ----
  for(int h=0;h<4;h++){
    const uint4* Bsrc = (const uint4*)(WheadT + (size_t)h*8192);
    uint4 bvr[4], avr[4];
#pragma unroll
    for(int it=0; it<4; it++){
      int idx = it*256 + t;
      bvr[it] = Bsrc[idx];
      int brow = idx>>4, u4 = idx&15;
      int grow = row0 + brow;
      uint4 v = {0,0,0,0};
      if(grow < NI){
        int co = (u4<8) ? (h*64 + u4*8) : (256 + h*64 + (u4-8)*8);
        v = *(const uint4*)(agg + (size_t)grow*512 + co);
      }
      avr[it] = v;
    }
    __syncthreads();
#pragma unroll
    for(int it=0; it<4; it++){
      int idx = it*256 + t;
      int brow = idx>>4, u4 = idx&15;
      *(uint4*)&Bs[brow][u4*8] = bvr[it];
      *(uint4*)&As[brow][u4*8] = avr[it];
    }
    __syncthreads();
    f32x4 acc0={0,0,0,0}, acc1={0,0,0,0}, acc2={0,0,0,0}, acc3={0,0,0,0};
#pragma unroll
    for(int ks=0; ks<4; ks++){
      bf16x8 af = *(const bf16x8*)&As[w*16 + r][q*8 + ks*32];
      bf16x8 b0 = *(const bf16x8*)&Bs[ 0 + r][q*8 + ks*32];
      bf16x8 b1 = *(const bf16x8*)&Bs[16 + r][q*8 + ks*32];
      bf16x8 b2 = *(const bf16x8*)&Bs[32 + r][q*8 + ks*32];
      bf16x8 b3 = *(const bf16x8*)&Bs[48 + r][q*8 + ks*32];
      acc0 = __builtin_amdgcn_mfma_f32_16x16x32_bf16(af,b0,acc0,0,0,0);
      acc1 = __builtin_amdgcn_mfma_f32_16x16x32_bf16(af,b1,acc1,0,0,0);
      acc2 = __builtin_amdgcn_mfma_f32_16x16x32_bf16(af,b2,acc2,0,0,0);
      acc3 = __builtin_amdgcn_mfma_f32_16x16x32_bf16(af,b3,acc3,0,0,0);
    }
    int crow = w*16 + q*4;
#pragma unroll
    for(int t2=0;t2<4;t2++){
      f32x4 a = (t2==0)?acc0 : (t2==1)?acc1 : (t2==2)?acc2 : acc3;
      int col = h*64 + t2*16 + r;
      float bcol = bias_comb[col];
#pragma unroll
      for(int rr=0;rr<4;rr++)
        interT[crow+rr][col] = f2bf(fmaxf(a[rr]+bcol, 0.f));
    }
  }
  __syncthreads();

  // ---- phase 2: GRU GEMM (A-fragments from LDS) + gates + output heads ----
  int arowl = w*16 + r;
  int arow  = row0 + arowl;
  int arc = arow < NI ? arow : NI-1;
  const float* h0r = h0 + (size_t)arc*64 + q*8;
  f32x4 acc[16];
#pragma unroll
  for(int i=0;i<16;i++) acc[i] = (f32x4){0,0,0,0};
#pragma unroll
  for(int ks=0; ks<10; ks++){
    bf16x8 af;
    if(ks < 8){
      af = *(const bf16x8*)&interT[arowl][ks*32 + q*8];
    } else {
      const float* hp = h0r + (ks-8)*32;
      float4 f0 = *(const float4*)(hp);
      float4 f1 = *(const float4*)(hp+4);
      uint4 P;
      P.x = pack2(f0.x,f0.y); P.y = pack2(f0.z,f0.w);
      P.z = pack2(f1.x,f1.y); P.w = pack2(f1.z,f1.w);
      *(uint4*)&af = P;
    }
    const uint4* bp = B2F + ks*1024 + lane;
#pragma unroll
    for(int tt=0;tt<16;tt++){
      uint4 bu = bp[tt*64];
      bf16x8 bfr; *(uint4*)&bfr = bu;
      acc[tt] = __builtin_amdgcn_mfma_f32_16x16x32_bf16(af, bfr, acc[tt], 0,0,0);
    }
  }
  float pk[4][8];
  float pv[4];
#pragma unroll
  for(int rr=0;rr<4;rr++){
    pv[rr]=0.f;
#pragma unroll
    for(int j=0;j<8;j++) pk[rr][j]=0.f;
  }
  int rbase = row0 + w*16 + q*4;
#pragma unroll
  for(int t2=0;t2<4;t2++){
    int c = t2*16 + r;
    float b0 = bias2[c], b1 = bias2[64+c], b2 = bias2[128+c], b3 = bias2[192+c];
    float wp[8];
#pragma unroll
    for(int j=0;j<8;j++) wp[j] = Wpi[c*8+j];
    float wv = Wv[c];
#pragma unroll
    for(int rr=0;rr<4;rr++){
      int row = rbase + rr;
      float g0 = acc[t2][rr]    + b0;
      float g1 = acc[t2+4][rr]  + b1;
      float g2 = acc[t2+8][rr]  + b2;
      float g3 = acc[t2+12][rr] + b3;
      float h0v = (row < NI) ? h0[(size_t)row*64 + c] : 0.f;
      float rg = 1.f/(1.f+__expf(-g0));
      float zg = 1.f/(1.f+__expf(-g1));
      float e2 = __expf(2.f*(g2 + rg*g3));
      float ng = 1.f - 2.f/(e2+1.f);
      float hh = (1.f-zg)*ng + zg*h0v;
      if(row < NI) out[450000 + (size_t)row*64 + c] = hh;
#pragma unroll
      for(int j=0;j<8;j++) pk[rr][j] += hh*wp[j];
      pv[rr] += hh*wv;
    }
  }
#pragma unroll
  for(int o=1;o<16;o<<=1){
#pragma unroll
    for(int rr=0;rr<4;rr++){
#pragma unroll
      for(int j=0;j<8;j++) pk[rr][j] += __shfl_xor(pk[rr][j], o, 64);
      pv[rr] += __shfl_xor(pv[rr], o, 64);
    }
  }
  if(r==0){
#pragma unroll
    for(int rr=0;rr<4;rr++){
      int row = rbase + rr;
      if(row < NI){
#pragma unroll
        for(int j=0;j<8;j++) out[(size_t)row*8 + j] = pk[rr][j] + bpi[j];
        out[400000 + row] = pv[rr] + bvp[0];
      }
    }
  }
}

extern "C" void kernel_launch(void* const* d_in, const int* in_sizes, int n_in,
                              void* d_out, int out_size, void* d_ws, size_t ws_size,
                              hipStream_t stream) {
  const float* x_int      = (const float*)d_in[0];
  const float* x_lane     = (const float*)d_in[1];
  const float* h0         = (const float*)d_in[2];
  const float* enc_int_W  = (const float*)d_in[3];
  const float* enc_int_b  = (const float*)d_in[4];
  const float* enc_lane_W = (const float*)d_in[5];
  const float* enc_lane_b = (const float*)d_in[6];
  const float* Wsrc_po    = (const float*)d_in[7];
  const float* Wdst_po    = (const float*)d_in[8];
  const float* att_src_po = (const float*)d_in[9];
  const float* att_dst_po = (const float*)d_in[10];
  const float* bias_po    = (const float*)d_in[11];
  const float* Wsrc_adj   = (const float*)d_in[12];
  const float* Wdst_adj   = (const float*)d_in[13];
  const float* att_src_adj= (const float*)d_in[14];
  const float* att_dst_adj= (const float*)d_in[15];
  const float* bias_adj   = (const float*)d_in[16];
  const float* gru_W_ih   = (const float*)d_in[17];
  const float* gru_W_hh   = (const float*)d_in[18];
  const float* gru_b_ih   = (const float*)d_in[19];
  const float* gru_b_hh   = (const float*)d_in[20];
  const float* W_pi       = (const float*)d_in[21];
  const float* b_pi       = (const float*)d_in[22];
  const float* W_v        = (const float*)d_in[23];
  const float* b_v        = (const float*)d_in[24];
  const int* src_po  = (const int*)d_in[25];
  const int* dst_po  = (const int*)d_in[26];
  const int* src_adj = (const int*)d_in[27];
  const int* dst_adj = (const int*)d_in[28];
  float* out = (float*)d_out;

  char* w = (char*)d_ws;
  size_t ofs = 0;
  auto alloc = [&](size_t bytes)->char*{
    char* p = w + ofs;
    ofs = (ofs + bytes + 255) & ~(size_t)255;
    return p;
  };
  u16*  e_lane   = (u16*)alloc((size_t)NL*64*2);
  u16*  e_int    = (u16*)alloc((size_t)NI*64*2);
  float* a_s_po  = (float*)alloc((size_t)NL*4*4);
  float* a_d_po  = (float*)alloc((size_t)NI*4*4);
  float* a_s_adj = (float*)alloc((size_t)NI*4*4);
  float* a_d_adj = (float*)alloc((size_t)NI*4*4);
  int*  cnt      = (int*)alloc((size_t)2*NI*4);
  int*  offA     = (int*)alloc((size_t)2*NI*4);
  int*  cur      = (int*)alloc((size_t)2*NI*4);
  int*  csr_po   = (int*)alloc((size_t)EPO*4);
  int*  csr_adj  = (int*)alloc((size_t)EADJ*4);
  float* pw_po   = (float*)alloc((size_t)EPO*4*4);
  float* pw_adj  = (float*)alloc((size_t)EADJ*4*4);
  int*  bsum     = (int*)alloc(2*64*4);
  u16*  agg      = (u16*)alloc((size_t)NI*512*2);
  u16*  WheadT   = (u16*)alloc(4*64*128*2);
  u16*  B2F      = (u16*)alloc(10*16*64*8*2);
  float* v4      = (float*)alloc(4*256*4);
  float* bias_comb = (float*)alloc(256*4);
  float* bias2   = (float*)alloc(256*4);
  (void)ws_size; (void)n_in; (void)in_sizes; (void)out_size;

  k0_prep<<<256, 256, 0, stream>>>(
      Wsrc_po, att_src_po, Wdst_po, att_dst_po,
      Wsrc_adj, att_src_adj, Wdst_adj, att_dst_adj,
      gru_W_ih, gru_W_hh, bias_po, bias_adj, gru_b_ih, gru_b_hh,
      v4, WheadT, B2F, bias_comb, bias2, cnt);
  k_enc<<<NLB+NIB+NHB, 256, 0, stream>>>(
      x_lane, enc_lane_W, enc_lane_b,
      x_int, enc_int_W, enc_int_b,
      v4 + 0, v4 + 256, v4 + 512, v4 + 768,
      e_lane, a_s_po, e_int, a_d_po, a_s_adj, a_d_adj,
      dst_po, dst_adj, cnt);
  k4a_scan<<<dim3(49,2), 1024, 0, stream>>>(cnt, offA, bsum);
  k4b_scanb<<<1, 128, 0, stream>>>(bsum);
  k4c_add<<<dim3(49,2), 1024, 0, stream>>>(offA, cur, bsum);
  k5_scatter<<<(EPO+EADJ+255)/256, 256, 0, stream>>>(src_po, dst_po, src_adj, dst_adj,
      a_s_po, a_d_po, a_s_adj, a_d_adj,
      cur, csr_po, csr_adj, pw_po, pw_adj);
  k6_agg<<<(NI+3)/4, 512, 0, stream>>>(offA, cnt, csr_po, csr_adj,
      pw_po, pw_adj, e_lane, e_int, agg);
  k8_fused<<<(NI+63)/64, 256, 0, stream>>>(agg, WheadT, bias_comb,
      (const uint4*)B2F, bias2, h0, W_pi, b_pi, W_v, b_v, out);
}

// Round 15
// 354.463 us; speedup vs baseline: 1.1418x; 1.0098x over previous
//
#include <hip/hip_runtime.h>

#define NI 50000
#define NL 400000
#define EPO 400000
#define EADJ 200000

// encoder tiling
#define K1_ITER 8
#define K2_ITER 4
#define K1_ROWS (32*K1_ITER)   // 256 rows/block
#define K2_ROWS (32*K2_ITER)   // 128 rows/block
#define NLB ((NL + K1_ROWS - 1)/K1_ROWS)   // 1563
#define NIB ((NI + K2_ROWS - 1)/K2_ROWS)   // 391
#define NHB ((EPO + EADJ + 255)/256)       // 2344 histogram blocks

typedef unsigned int u32;
typedef unsigned short u16;
typedef short bf16x8 __attribute__((ext_vector_type(8)));
typedef float f32x4 __attribute__((ext_vector_type(4)));

__device__ __forceinline__ float bf2f(u16 h){ return __uint_as_float(((u32)h)<<16); }
__device__ __forceinline__ u16 f2bf(float f){
  u32 u = __float_as_uint(f);
  u += 0x7FFFu + ((u>>16)&1u);
  return (u16)(u>>16);
}
__device__ __forceinline__ u32 pack2(float a, float b){
  return (u32)f2bf(a) | ((u32)f2bf(b)<<16);
}

// GRU combined weight value: maps [inter(256) | h0(64)] -> [r_sum, z_sum, i_n, h_n]
__device__ __forceinline__ float b2_val(
    const float* __restrict__ W_ih, const float* __restrict__ W_hh, int m, int k)
{
  if(k < 256){ return (m<192) ? W_ih[m*256+k] : 0.f; }
  int kk = k-256;
  if(m<128) return W_hh[m*64+kk];
  if(m>=192) return W_hh[(m-64)*64+kk];
  return 0.f;
}

// ---------------- K0: weight prep + cnt/cursor zeroing ----------------
// WheadF (verified R13): u4 index = ((h*4+kt)*4+ct)*64 + lane; 8 bf16 each:
//   value = B[n=ct*16+(lane&15)][k'=kt*32+(lane>>4)*8+j]
//   k'<64 -> Wsrc_po[k'][h*64+n] ; else Wsrc_adj[k'-64][h*64+n]
__global__ __launch_bounds__(256) void k0_prep(
    const float* __restrict__ Wsrc_po, const float* __restrict__ att_src_po,
    const float* __restrict__ Wdst_po, const float* __restrict__ att_dst_po,
    const float* __restrict__ Wsrc_adj, const float* __restrict__ att_src_adj,
    const float* __restrict__ Wdst_adj, const float* __restrict__ att_dst_adj,
    const float* __restrict__ W_ih, const float* __restrict__ W_hh,
    const float* __restrict__ bias_po, const float* __restrict__ bias_adj,
    const float* __restrict__ b_ih, const float* __restrict__ b_hh,
    float* __restrict__ v4, u16* __restrict__ WheadF, u16* __restrict__ B2F,
    float* __restrict__ bias_comb, float* __restrict__ bias2,
    int* __restrict__ cnt, int* __restrict__ cursor)
{
  const int T0 = 1024, T1 = 4*4*4*64*8, T2 = 10*16*64*8;
  const int TC = 2*NI;
  int total = T0 + T1 + T2 + 256 + 256 + TC + 2;
  for(int t = blockIdx.x*256 + threadIdx.x; t < total; t += gridDim.x*256){
    if(t < T0){
      int which = t>>8, hc = t&255, h = hc>>6, c = hc&63;
      const float *W, *att;
      if(which==0){ W=Wsrc_po;  att=att_src_po; }
      else if(which==1){ W=Wdst_po;  att=att_dst_po; }
      else if(which==2){ W=Wsrc_adj; att=att_src_adj; }
      else { W=Wdst_adj; att=att_dst_adj; }
      float s=0.f;
      for(int j=0;j<64;j++) s += W[c*256 + h*64 + j]*att[h*64+j];
      v4[which*256 + hc] = s;
    } else if(t < T0 + T1){
      int i = t - T0;
      int j = i&7;
      int u4 = i>>3;
      int lane = u4&63;
      int rem = u4>>6;          // h*16 + kt*4 + ct
      int ct = rem&3, kt = (rem>>2)&3, h = rem>>4;
      int r = lane&15, qb = lane>>4;
      int kp = kt*32 + qb*8 + j;
      int n = ct*16 + r;
      float val = (kp<64) ? Wsrc_po[kp*256 + h*64 + n]
                          : Wsrc_adj[(kp-64)*256 + h*64 + n];
      WheadF[i] = f2bf(val);
    } else if(t < T0 + T1 + T2){
      int i = t - (T0+T1);
      int j = i&7;
      int u4 = i>>3;
      int kstep = u4>>10, rem = u4&1023, tile = rem>>6, lane = rem&63;
      int col = tile*16 + (lane&15);
      int k = kstep*32 + (lane>>4)*8 + j;
      B2F[i] = f2bf(b2_val(W_ih, W_hh, col, k));
    } else if(t < T0 + T1 + T2 + 256){
      int m = t - (T0+T1+T2);
      bias_comb[m] = bias_po[m] + bias_adj[m];
    } else if(t < T0 + T1 + T2 + 512){
      int m = t - (T0+T1+T2+256);
      float v;
      if(m<128) v = b_ih[m] + b_hh[m];
      else if(m<192) v = b_ih[m];
      else v = b_hh[m-64];
      bias2[m] = v;
    } else if(t < T0 + T1 + T2 + 512 + TC){
      cnt[t - (T0+T1+T2+512)] = 0;
    } else {
      cursor[t - (T0+T1+T2+512+TC)] = 0;
    }
  }
}

// ---------------- K_ENC: fused lane+int encoders + edge histogram (unchanged) ----------------
__global__ __launch_bounds__(256) void k_enc(
    const float* __restrict__ x_lane, const float* __restrict__ Wl, const float* __restrict__ bl,
    const float* __restrict__ x_int,  const float* __restrict__ Wi, const float* __restrict__ bi,
    const float* __restrict__ v_sp, const float* __restrict__ v_dp,
    const float* __restrict__ v_sa, const float* __restrict__ v_da,
    u16* __restrict__ e_lane, float* __restrict__ a_s_po,
    u16* __restrict__ e_int, float* __restrict__ a_dp, float* __restrict__ a_sa,
    float* __restrict__ a_da,
    const int* __restrict__ dst_po, const int* __restrict__ dst_adj,
    int* __restrict__ cnt)
{
  int t = threadIdx.x;
  int wv = t>>6, l = t&63;
  int g = l&7, m = l>>3;
  int blk = blockIdx.x;
  if(blk < NLB){
    float wreg[12][8], breg[8];
#pragma unroll
    for(int k=0;k<12;k++){
      float4 w0 = *(const float4*)(Wl + k*64 + g*8);
      float4 w1 = *(const float4*)(Wl + k*64 + g*8 + 4);
      wreg[k][0]=w0.x; wreg[k][1]=w0.y; wreg[k][2]=w0.z; wreg[k][3]=w0.w;
      wreg[k][4]=w1.x; wreg[k][5]=w1.y; wreg[k][6]=w1.z; wreg[k][7]=w1.w;
    }
    {
      float4 b0 = *(const float4*)(bl + g*8);
      float4 b1 = *(const float4*)(bl + g*8 + 4);
      breg[0]=b0.x; breg[1]=b0.y; breg[2]=b0.z; breg[3]=b0.w;
      breg[4]=b1.x; breg[5]=b1.y; breg[6]=b1.z; breg[7]=b1.w;
    }
    int rowbase = blk*K1_ROWS + wv*(8*K1_ITER) + m;
    float4 Aa={0,0,0,0}, Ab={0,0,0,0}, Ac={0,0,0,0};
    float4 Ba={0,0,0,0}, Bb={0,0,0,0}, Bc={0,0,0,0};
    if(rowbase < NL){
      const float4* xp = (const float4*)(x_lane + (size_t)rowbase*12);
      Aa = xp[0]; Ab = xp[1]; Ac = xp[2];
    }
    if(rowbase+8 < NL){
      const float4* xp = (const float4*)(x_lane + (size_t)(rowbase+8)*12);
      Ba = xp[0]; Bb = xp[1]; Bc = xp[2];
    }
#pragma unroll
    for(int it=0; it<K1_ITER; it++){
      int row = rowbase + it*8;
      float4 Ca={0,0,0,0}, Cb={0,0,0,0}, Cc={0,0,0,0};
      if(it+2 < K1_ITER && row+16 < NL){
        const float4* xp = (const float4*)(x_lane + (size_t)(row+16)*12);
        Ca = xp[0]; Cb = xp[1]; Cc = xp[2];
      }
      float xv[12];
      xv[0]=Aa.x; xv[1]=Aa.y; xv[2]=Aa.z; xv[3]=Aa.w;
      xv[4]=Ab.x; xv[5]=Ab.y; xv[6]=Ab.z; xv[7]=Ab.w;
      xv[8]=Ac.x; xv[9]=Ac.y; xv[10]=Ac.z; xv[11]=Ac.w;
      float acc[8];
#pragma unroll
      for(int j=0;j<8;j++) acc[j]=breg[j];
#pragma unroll
      for(int k=0;k<12;k++){
        float xk = xv[k];
#pragma unroll
        for(int j=0;j<8;j++) acc[j] += xk*wreg[k][j];
      }
      float e[8];
#pragma unroll
      for(int j=0;j<8;j++) e[j] = fmaxf(acc[j], 0.f);
      float as[4];
#pragma unroll
      for(int h=0;h<4;h++){
        float4 v0 = *(const float4*)(v_sp + h*64 + g*8);
        float4 v1 = *(const float4*)(v_sp + h*64 + g*8 + 4);
        as[h] = e[0]*v0.x + e[1]*v0.y + e[2]*v0.z + e[3]*v0.w
              + e[4]*v1.x + e[5]*v1.y + e[6]*v1.z + e[7]*v1.w;
      }
#pragma unroll
      for(int o=1;o<8;o<<=1){
#pragma unroll
        for(int h=0;h<4;h++) as[h] += __shfl_xor(as[h], o, 64);
      }
      if(row < NL){
        uint4 P;
        P.x = pack2(e[0],e[1]); P.y = pack2(e[2],e[3]);
        P.z = pack2(e[4],e[5]); P.w = pack2(e[6],e[7]);
        ((uint4*)e_lane)[(size_t)row*8 + g] = P;
        if(g==0){
          float4 A; A.x=as[0]; A.y=as[1]; A.z=as[2]; A.w=as[3];
          *(float4*)(a_s_po + (size_t)row*4) = A;
        }
      }
      Aa=Ba; Ab=Bb; Ac=Bc;
      Ba=Ca; Bb=Cb; Bc=Cc;
    }
  } else if(blk < NLB + NIB){
    int b2 = blk - NLB;
    float breg[8];
    {
      float4 b0 = *(const float4*)(bi + g*8);
      float4 b1 = *(const float4*)(bi + g*8 + 4);
      breg[0]=b0.x; breg[1]=b0.y; breg[2]=b0.z; breg[3]=b0.w;
      breg[4]=b1.x; breg[5]=b1.y; breg[6]=b1.z; breg[7]=b1.w;
    }
    int rowbase = b2*K2_ROWS + wv*(8*K2_ITER) + m;
#pragma unroll
    for(int it=0; it<K2_ITER; it++){
      int row = rowbase + it*8;
      float xv[16];
      if(row < NI){
        const float4* xp = (const float4*)(x_int + (size_t)row*16);
#pragma unroll
        for(int q=0;q<4;q++){
          float4 xq = xp[q];
          xv[q*4]=xq.x; xv[q*4+1]=xq.y; xv[q*4+2]=xq.z; xv[q*4+3]=xq.w;
        }
      } else {
#pragma unroll
        for(int k=0;k<16;k++) xv[k]=0.f;
      }
      float acc[8];
#pragma unroll
      for(int j=0;j<8;j++) acc[j]=breg[j];
#pragma unroll
      for(int k=0;k<16;k++){
        float4 w0 = *(const float4*)(Wi + k*64 + g*8);
        float4 w1 = *(const float4*)(Wi + k*64 + g*8 + 4);
        float xk = xv[k];
        acc[0] += xk*w0.x; acc[1] += xk*w0.y; acc[2] += xk*w0.z; acc[3] += xk*w0.w;
        acc[4] += xk*w1.x; acc[5] += xk*w1.y; acc[6] += xk*w1.z; acc[7] += xk*w1.w;
      }
      float e[8];
#pragma unroll
      for(int j=0;j<8;j++) e[j] = fmaxf(acc[j], 0.f);
      float ad[4], sa[4], da[4];
#pragma unroll
      for(int h=0;h<4;h++){
        float4 v0, v1;
        v0 = *(const float4*)(v_dp + h*64 + g*8); v1 = *(const float4*)(v_dp + h*64 + g*8 + 4);
        ad[h] = e[0]*v0.x + e[1]*v0.y + e[2]*v0.z + e[3]*v0.w
              + e[4]*v1.x + e[5]*v1.y + e[6]*v1.z + e[7]*v1.w;
        v0 = *(const float4*)(v_sa + h*64 + g*8); v1 = *(const float4*)(v_sa + h*64 + g*8 + 4);
        sa[h] = e[0]*v0.x + e[1]*v0.y + e[2]*v0.z + e[3]*v0.w
              + e[4]*v1.x + e[5]*v1.y + e[6]*v1.z + e[7]*v1.w;
        v0 = *(const float4*)(v_da + h*64 + g*8); v1 = *(const float4*)(v_da + h*64 + g*8 + 4);
        da[h] = e[0]*v0.x + e[1]*v0.y + e[2]*v0.z + e[3]*v0.w
              + e[4]*v1.x + e[5]*v1.y + e[6]*v1.z + e[7]*v1.w;
      }
#pragma unroll
      for(int o=1;o<8;o<<=1){
#pragma unroll
        for(int h=0;h<4;h++){
          ad[h] += __shfl_xor(ad[h], o, 64);
          sa[h] += __shfl_xor(sa[h], o, 64);
          da[h] += __shfl_xor(da[h], o, 64);
        }
      }
      if(row < NI){
        uint4 P;
        P.x = pack2(e[0],e[1]); P.y = pack2(e[2],e[3]);
        P.z = pack2(e[4],e[5]); P.w = pack2(e[6],e[7]);
        ((uint4*)e_int)[(size_t)row*8 + g] = P;
        if(g==0){
          float4 A;
          A.x=ad[0]; A.y=ad[1]; A.z=ad[2]; A.w=ad[3]; *(float4*)(a_dp + (size_t)row*4) = A;
          A.x=sa[0]; A.y=sa[1]; A.z=sa[2]; A.w=sa[3]; *(float4*)(a_sa + (size_t)row*4) = A;
          A.x=da[0]; A.y=da[1]; A.z=da[2]; A.w=da[3]; *(float4*)(a_da + (size_t)row*4) = A;
        }
      }
    }
  } else {
    int i = (blk - NLB - NIB)*256 + t;
    if(i < EPO) atomicAdd(&cnt[dst_po[i]], 1);
    else if(i < EPO+EADJ) atomicAdd(&cnt[NI + dst_adj[i-EPO]], 1);
  }
}

// ---------------- K4: single-kernel order-free scan (wave-local scan + cursor atomic) ----------------
// dst segments are contiguous but placed in arbitrary order -- valid, since off/cnt used consistently.
__global__ __launch_bounds__(256) void k4_scan(
    const int* __restrict__ cnt, int* __restrict__ offA, int* __restrict__ cur,
    int* __restrict__ cursor)
{
  int y = blockIdx.y;
  int wid = threadIdx.x>>6, lane = threadIdx.x&63;
  int base_i = (blockIdx.x*4 + wid)*256;
  int v[4], inc[4], ctot[4];
#pragma unroll
  for(int c=0;c<4;c++){
    int i = base_i + c*64 + lane;
    v[c] = (i<NI) ? cnt[(size_t)y*NI+i] : 0;
    int x = v[c];
#pragma unroll
    for(int o=1;o<64;o<<=1){
      int tt = __shfl_up(x,o,64);
      if(lane>=o) x += tt;
    }
    inc[c] = x;
    ctot[c] = __shfl(x, 63, 64);
  }
  int cpre[4];
  cpre[0]=0;
  cpre[1]=ctot[0];
  cpre[2]=cpre[1]+ctot[1];
  cpre[3]=cpre[2]+ctot[2];
  int wtot = cpre[3]+ctot[3];
  int base = 0;
  if(lane==0) base = atomicAdd(&cursor[y], wtot);
  base = __shfl(base, 0, 64);
#pragma unroll
  for(int c=0;c<4;c++){
    int i = base_i + c*64 + lane;
    if(i<NI){
      int o = base + cpre[c] + inc[c] - v[c];
      offA[(size_t)y*NI+i] = o;
      cur[(size_t)y*NI+i]  = o;
    }
  }
}

// ---------------- K5: scatter src + per-edge softmax numerator weights ----------------
__global__ __launch_bounds__(256) void k5_scatter(
    const int* __restrict__ src_po, const int* __restrict__ dst_po,
    const int* __restrict__ src_adj, const int* __restrict__ dst_adj,
    const float* __restrict__ a_s_po, const float* __restrict__ a_d_po,
    const float* __restrict__ a_s_adj, const float* __restrict__ a_d_adj,
    int* __restrict__ cur, int* __restrict__ csr_po, int* __restrict__ csr_adj,
    float* __restrict__ pw_po, float* __restrict__ pw_adj)
{
  int i = blockIdx.x*256 + threadIdx.x;
  if(i < EPO){
    int s = src_po[i];
    int d = dst_po[i];
    int p = atomicAdd(&cur[d],1);
    csr_po[p] = s;
    float4 as = *(const float4*)(a_s_po + (size_t)s*4);
    float4 ad = *(const float4*)(a_d_po + (size_t)d*4);
    float4 pv;
    float x;
    x = as.x+ad.x; pv.x = __expf(x>0.f?x:0.2f*x);
    x = as.y+ad.y; pv.y = __expf(x>0.f?x:0.2f*x);
    x = as.z+ad.z; pv.z = __expf(x>0.f?x:0.2f*x);
    x = as.w+ad.w; pv.w = __expf(x>0.f?x:0.2f*x);
    *(float4*)(pw_po + (size_t)p*4) = pv;
  } else if(i < EPO+EADJ){
    int e = i-EPO;
    int s = src_adj[e];
    int d = dst_adj[e];
    int p = atomicAdd(&cur[NI+d],1);
    csr_adj[p] = s;
    float4 as = *(const float4*)(a_s_adj + (size_t)s*4);
    float4 ad = *(const float4*)(a_d_adj + (size_t)d*4);
    float4 pv;
    float x;
    x = as.x+ad.x; pv.x = __expf(x>0.f?x:0.2f*x);
    x = as.y+ad.y; pv.y = __expf(x>0.f?x:0.2f*x);
    x = as.z+ad.z; pv.z = __expf(x>0.f?x:0.2f*x);
    x = as.w+ad.w; pv.w = __expf(x>0.f?x:0.2f*x);
    *(float4*)(pw_adj + (size_t)p*4) = pv;
  }
}

// ---------------- K6: weighted-sum aggregation, 4-way independent edge chains ----------------
__device__ __forceinline__ void agg_rel(
    int beg, int n, int lane,
    const int* __restrict__ csr, const float* __restrict__ pw,
    const u16* __restrict__ emat, u16* __restrict__ aggrow)
{
  float l0=0,l1=0,l2=0,l3=0;
  float c0=0,c1=0,c2=0,c3=0;
  for(int base=0;base<n;base+=64){
    int m = n-base; if(m>64) m=64;
    int sv_ = (lane<m) ? csr[beg+base+lane] : 0;
    int t2=0;
    for(; t2+3<m; t2+=4){
      int s0 = __shfl(sv_, t2,   64);
      int s1 = __shfl(sv_, t2+1, 64);
      int s2 = __shfl(sv_, t2+2, 64);
      int s3 = __shfl(sv_, t2+3, 64);
      float4 p0 = *(const float4*)(pw + (size_t)(beg+base+t2  )*4);
      float4 p1 = *(const float4*)(pw + (size_t)(beg+base+t2+1)*4);
      float4 p2 = *(const float4*)(pw + (size_t)(beg+base+t2+2)*4);
      float4 p3 = *(const float4*)(pw + (size_t)(beg+base+t2+3)*4);
      float e0 = bf2f(emat[(size_t)s0*64+lane]);
      float e1 = bf2f(emat[(size_t)s1*64+lane]);
      float e2 = bf2f(emat[(size_t)s2*64+lane]);
      float e3 = bf2f(emat[(size_t)s3*64+lane]);
      c0 += p0.x*e0; c1 += p0.y*e0; c2 += p0.z*e0; c3 += p0.w*e0;
      l0 += p0.x;    l1 += p0.y;    l2 += p0.z;    l3 += p0.w;
      c0 += p1.x*e1; c1 += p1.y*e1; c2 += p1.z*e1; c3 += p1.w*e1;
      l0 += p1.x;    l1 += p1.y;    l2 += p1.z;    l3 += p1.w;
      c0 += p2.x*e2; c1 += p2.y*e2; c2 += p2.z*e2; c3 += p2.w*e2;
      l0 += p2.x;    l1 += p2.y;    l2 += p2.z;    l3 += p2.w;
      c0 += p3.x*e3; c1 += p3.y*e3; c2 += p3.z*e3; c3 += p3.w*e3;
      l0 += p3.x;    l1 += p3.y;    l2 += p3.z;    l3 += p3.w;
    }
    for(; t2<m; t2++){
      int s0 = __shfl(sv_, t2, 64);
      float4 p0 = *(const float4*)(pw + (size_t)(beg+base+t2)*4);
      float e0 = bf2f(emat[(size_t)s0*64+lane]);
      c0 += p0.x*e0; c1 += p0.y*e0; c2 += p0.z*e0; c3 += p0.w*e0;
      l0 += p0.x;    l1 += p0.y;    l2 += p0.z;    l3 += p0.w;
    }
  }
  aggrow[lane]       = f2bf(n>0 ? c0/l0 : 0.f);
  aggrow[64+lane]    = f2bf(n>0 ? c1/l1 : 0.f);
  aggrow[128+lane]   = f2bf(n>0 ? c2/l2 : 0.f);
  aggrow[192+lane]   = f2bf(n>0 ? c3/l3 : 0.f);
}

__global__ __launch_bounds__(512) void k6_agg(
    const int* __restrict__ off, const int* __restrict__ cnt,
    const int* __restrict__ csr_po, const int* __restrict__ csr_adj,
    const float* __restrict__ pw_po, const float* __restrict__ pw_adj,
    const u16* __restrict__ e_lane, const u16* __restrict__ e_int,
    u16* __restrict__ agg)
{
  int wave=threadIdx.x>>6, lane=threadIdx.x&63;
  int d = blockIdx.x*4 + (wave&3);
  if(d>=NI) return;
  if(wave < 4)
    agg_rel(off[d],    cnt[d],    lane, csr_po,  pw_po,  e_lane, agg + (size_t)d*512);
  else
    agg_rel(off[NI+d], cnt[NI+d], lane, csr_adj, pw_adj, e_int,  agg + (size_t)d*512 + 256);
}

// ---------------- K8 v3: A staged wave-private (coalesced), B fragment-direct (WheadF);
//                  + GRU GEMM + gates + output heads ----------------
__global__ __launch_bounds__(256) void k8_fused(
    const u16* __restrict__ agg, const uint4* __restrict__ WheadF,
    const float* __restrict__ bias_comb,
    const uint4* __restrict__ B2F, const float* __restrict__ bias2,
    const float* __restrict__ h0,
    const float* __restrict__ Wpi, const float* __restrict__ bpi,
    const float* __restrict__ Wv, const float* __restrict__ bvp,
    float* __restrict__ out)
{
  __shared__ u16 As[64][136];      // wave-private 16-row bands
  __shared__ u16 interT[64][264];  // wave-private 16-row bands
  int t=threadIdx.x, w=t>>6, lane=t&63;
  int r = lane&15, q = lane>>4;
  int row0 = blockIdx.x*64;

  // ---- phase 1: per-head GEMMs; wave w computes rows w*16..+15, all heads ----
  for(int h=0;h<4;h++){
    // stage A band: rows w*16..+15 x 128 head-h cols; 256B-per-4-rows coalesced
#pragma unroll
    for(int it=0; it<4; it++){
      int lrow = it*4 + q;
      int grow = row0 + w*16 + lrow;
      int arc = grow < NI ? grow : NI-1;
      int u4p = lane&15;
      int co = (u4p<8) ? (h*64 + u4p*8) : (256 + h*64 + (u4p-8)*8);
      uint4 v = *(const uint4*)(agg + (size_t)arc*512 + co);
      *(uint4*)&As[w*16 + lrow][u4p*8] = v;
    }
    __syncthreads();   // intra-wave LDS write->read fence (bands are wave-private)
    bf16x8 af[4];
#pragma unroll
    for(int kt=0;kt<4;kt++)
      af[kt] = *(const bf16x8*)&As[w*16 + r][q*8 + kt*32];
    const uint4* BF = WheadF + (size_t)h*16*64;
#pragma unroll
    for(int ct=0; ct<4; ct++){
      f32x4 facc = {0,0,0,0};
#pragma unroll
      for(int kt=0; kt<4; kt++){
        uint4 bu = BF[(kt*4 + ct)*64 + lane];
        bf16x8 bfr; *(uint4*)&bfr = bu;
        facc = __builtin_amdgcn_mfma_f32_16x16x32_bf16(af[kt], bfr, facc, 0,0,0);
      }
      int col = h*64 + ct*16 + r;
      float bcol = bias_comb[col];
#pragma unroll
      for(int rr=0; rr<4; rr++)
        interT[w*16 + q*4 + rr][col] = f2bf(fmaxf(facc[rr]+bcol, 0.f));
    }
  }
  __syncthreads();

  // ---- phase 2: GRU GEMM (A-fragments from LDS band) + gates + output heads ----
  int arowl = w*16 + r;
  int arow  = row0 + arowl;
  int arc = arow < NI ? arow : NI-1;
  const float* h0r = h0 + (size_t)arc*64 + q*8;
  f32x4 acc[16];
#pragma unroll
  for(int i=0;i<16;i++) acc[i] = (f32x4){0,0,0,0};
#pragma unroll
  for(int ks=0; ks<10; ks++){
    bf16x8 af;
    if(ks < 8){
      af = *(const bf16x8*)&interT[arowl][ks*32 + q*8];
    } else {
      const float* hp = h0r + (ks-8)*32;
      float4 f0 = *(const float4*)(hp);
      float4 f1 = *(const float4*)(hp+4);
      uint4 P;
      P.x = pack2(f0.x,f0.y); P.y = pack2(f0.z,f0.w);
      P.z = pack2(f1.x,f1.y); P.w = pack2(f1.z,f1.w);
      *(uint4*)&af = P;
    }
    const uint4* bp = B2F + ks*1024 + lane;
#pragma unroll
    for(int tt=0;tt<16;tt++){
      uint4 bu = bp[tt*64];
      bf16x8 bfr; *(uint4*)&bfr = bu;
      acc[tt] = __builtin_amdgcn_mfma_f32_16x16x32_bf16(af, bfr, acc[tt], 0,0,0);
    }
  }
  float pk[4][8];
  float pv[4];
#pragma unroll
  for(int rr=0;rr<4;rr++){
    pv[rr]=0.f;
#pragma unroll
    for(int j=0;j<8;j++) pk[rr][j]=0.f;
  }
  int rbase = row0 + w*16 + q*4;
#pragma unroll
  for(int t2=0;t2<4;t2++){
    int c = t2*16 + r;
    float b0 = bias2[c], b1 = bias2[64+c], b2 = bias2[128+c], b3 = bias2[192+c];
    float wp[8];
#pragma unroll
    for(int j=0;j<8;j++) wp[j] = Wpi[c*8+j];
    float wv = Wv[c];
#pragma unroll
    for(int rr=0;rr<4;rr++){
      int row = rbase + rr;
      float g0 = acc[t2][rr]    + b0;
      float g1 = acc[t2+4][rr]  + b1;
      float g2 = acc[t2+8][rr]  + b2;
      float g3 = acc[t2+12][rr] + b3;
      float h0v = (row < NI) ? h0[(size_t)row*64 + c] : 0.f;
      float rg = 1.f/(1.f+__expf(-g0));
      float zg = 1.f/(1.f+__expf(-g1));
      float e2 = __expf(2.f*(g2 + rg*g3));
      float ng = 1.f - 2.f/(e2+1.f);
      float hh = (1.f-zg)*ng + zg*h0v;
      if(row < NI) out[450000 + (size_t)row*64 + c] = hh;
#pragma unroll
      for(int j=0;j<8;j++) pk[rr][j] += hh*wp[j];
      pv[rr] += hh*wv;
    }
  }
#pragma unroll
  for(int o=1;o<16;o<<=1){
#pragma unroll
    for(int rr=0;rr<4;rr++){
#pragma unroll
      for(int j=0;j<8;j++) pk[rr][j] += __shfl_xor(pk[rr][j], o, 64);
      pv[rr] += __shfl_xor(pv[rr], o, 64);
    }
  }
  if(r==0){
#pragma unroll
    for(int rr=0;rr<4;rr++){
      int row = rbase + rr;
      if(row < NI){
#pragma unroll
        for(int j=0;j<8;j++) out[(size_t)row*8 + j] = pk[rr][j] + bpi[j];
        out[400000 + row] = pv[rr] + bvp[0];
      }
    }
  }
}

extern "C" void kernel_launch(void* const* d_in, const int* in_sizes, int n_in,
                              void* d_out, int out_size, void* d_ws, size_t ws_size,
                              hipStream_t stream) {
  const float* x_int      = (const float*)d_in[0];
  const float* x_lane     = (const float*)d_in[1];
  const float* h0         = (const float*)d_in[2];
  const float* enc_int_W  = (const float*)d_in[3];
  const float* enc_int_b  = (const float*)d_in[4];
  const float* enc_lane_W = (const float*)d_in[5];
  const float* enc_lane_b = (const float*)d_in[6];
  const float* Wsrc_po    = (const float*)d_in[7];
  const float* Wdst_po    = (const float*)d_in[8];
  const float* att_src_po = (const float*)d_in[9];
  const float* att_dst_po = (const float*)d_in[10];
  const float* bias_po    = (const float*)d_in[11];
  const float* Wsrc_adj   = (const float*)d_in[12];
  const float* Wdst_adj   = (const float*)d_in[13];
  const float* att_src_adj= (const float*)d_in[14];
  const float* att_dst_adj= (const float*)d_in[15];
  const float* bias_adj   = (const float*)d_in[16];
  const float* gru_W_ih   = (const float*)d_in[17];
  const float* gru_W_hh   = (const float*)d_in[18];
  const float* gru_b_ih   = (const float*)d_in[19];
  const float* gru_b_hh   = (const float*)d_in[20];
  const float* W_pi       = (const float*)d_in[21];
  const float* b_pi       = (const float*)d_in[22];
  const float* W_v        = (const float*)d_in[23];
  const float* b_v        = (const float*)d_in[24];
  const int* src_po  = (const int*)d_in[25];
  const int* dst_po  = (const int*)d_in[26];
  const int* src_adj = (const int*)d_in[27];
  const int* dst_adj = (const int*)d_in[28];
  float* out = (float*)d_out;

  char* w = (char*)d_ws;
  size_t ofs = 0;
  auto alloc = [&](size_t bytes)->char*{
    char* p = w + ofs;
    ofs = (ofs + bytes + 255) & ~(size_t)255;
    return p;
  };
  u16*  e_lane   = (u16*)alloc((size_t)NL*64*2);
  u16*  e_int    = (u16*)alloc((size_t)NI*64*2);
  float* a_s_po  = (float*)alloc((size_t)NL*4*4);
  float* a_d_po  = (float*)alloc((size_t)NI*4*4);
  float* a_s_adj = (float*)alloc((size_t)NI*4*4);
  float* a_d_adj = (float*)alloc((size_t)NI*4*4);
  int*  cnt      = (int*)alloc((size_t)2*NI*4);
  int*  offA     = (int*)alloc((size_t)2*NI*4);
  int*  cur      = (int*)alloc((size_t)2*NI*4);
  int*  csr_po   = (int*)alloc((size_t)EPO*4);
  int*  csr_adj  = (int*)alloc((size_t)EADJ*4);
  float* pw_po   = (float*)alloc((size_t)EPO*4*4);
  float* pw_adj  = (float*)alloc((size_t)EADJ*4*4);
  int*  cursor   = (int*)alloc(2*4);
  u16*  agg      = (u16*)alloc((size_t)NI*512*2);
  u16*  WheadF   = (u16*)alloc(4*4*4*64*8*2);
  u16*  B2F      = (u16*)alloc(10*16*64*8*2);
  float* v4      = (float*)alloc(4*256*4);
  float* bias_comb = (float*)alloc(256*4);
  float* bias2   = (float*)alloc(256*4);
  (void)ws_size; (void)n_in; (void)in_sizes; (void)out_size;

  k0_prep<<<256, 256, 0, stream>>>(
      Wsrc_po, att_src_po, Wdst_po, att_dst_po,
      Wsrc_adj, att_src_adj, Wdst_adj, att_dst_adj,
      gru_W_ih, gru_W_hh, bias_po, bias_adj, gru_b_ih, gru_b_hh,
      v4, WheadF, B2F, bias_comb, bias2, cnt, cursor);
  k_enc<<<NLB+NIB+NHB, 256, 0, stream>>>(
      x_lane, enc_lane_W, enc_lane_b,
      x_int, enc_int_W, enc_int_b,
      v4 + 0, v4 + 256, v4 + 512, v4 + 768,
      e_lane, a_s_po, e_int, a_d_po, a_s_adj, a_d_adj,
      dst_po, dst_adj, cnt);
  k4_scan<<<dim3((NI+1023)/1024, 2), 256, 0, stream>>>(cnt, offA, cur, cursor);
  k5_scatter<<<(EPO+EADJ+255)/256, 256, 0, stream>>>(src_po, dst_po, src_adj, dst_adj,
      a_s_po, a_d_po, a_s_adj, a_d_adj,
      cur, csr_po, csr_adj, pw_po, pw_adj);
  k6_agg<<<(NI+3)/4, 512, 0, stream>>>(offA, cnt, csr_po, csr_adj,
      pw_po, pw_adj, e_lane, e_int, agg);
  k8_fused<<<(NI+63)/64, 256, 0, stream>>>(agg, (const uint4*)WheadF, bias_comb,
      (const uint4*)B2F, bias2, h0, W_pi, b_pi, W_v, b_v, out);
}

// Round 16
// 346.687 us; speedup vs baseline: 1.1674x; 1.0224x over previous
//
#include <hip/hip_runtime.h>

#define NI 50000
#define NL 400000
#define EPO 400000
#define EADJ 200000

// encoder tiling
#define K1_ITER 8
#define K2_ITER 4
#define K1_ROWS (32*K1_ITER)   // 256 rows/block
#define K2_ROWS (32*K2_ITER)   // 128 rows/block
#define NLB ((NL + K1_ROWS - 1)/K1_ROWS)   // 1563
#define NIB ((NI + K2_ROWS - 1)/K2_ROWS)   // 391
#define NHB ((EPO + EADJ + 255)/256)       // 2344 histogram blocks

typedef unsigned int u32;
typedef unsigned short u16;
typedef short bf16x8 __attribute__((ext_vector_type(8)));
typedef float f32x4 __attribute__((ext_vector_type(4)));

__device__ __forceinline__ float bf2f(u16 h){ return __uint_as_float(((u32)h)<<16); }
__device__ __forceinline__ u16 f2bf(float f){
  u32 u = __float_as_uint(f);
  u += 0x7FFFu + ((u>>16)&1u);
  return (u16)(u>>16);
}
__device__ __forceinline__ u32 pack2(float a, float b){
  return (u32)f2bf(a) | ((u32)f2bf(b)<<16);
}

// GRU combined weight value: maps [inter(256) | h0(64)] -> [r_sum, z_sum, i_n, h_n]
__device__ __forceinline__ float b2_val(
    const float* __restrict__ W_ih, const float* __restrict__ W_hh, int m, int k)
{
  if(k < 256){ return (m<192) ? W_ih[m*256+k] : 0.f; }
  int kk = k-256;
  if(m<128) return W_hh[m*64+kk];
  if(m>=192) return W_hh[(m-64)*64+kk];
  return 0.f;
}

// ---------------- K0: weight prep + cnt/cursor zeroing ----------------
__global__ __launch_bounds__(256) void k0_prep(
    const float* __restrict__ Wsrc_po, const float* __restrict__ att_src_po,
    const float* __restrict__ Wdst_po, const float* __restrict__ att_dst_po,
    const float* __restrict__ Wsrc_adj, const float* __restrict__ att_src_adj,
    const float* __restrict__ Wdst_adj, const float* __restrict__ att_dst_adj,
    const float* __restrict__ W_ih, const float* __restrict__ W_hh,
    const float* __restrict__ bias_po, const float* __restrict__ bias_adj,
    const float* __restrict__ b_ih, const float* __restrict__ b_hh,
    float* __restrict__ v4, u16* __restrict__ WheadF, u16* __restrict__ B2F,
    float* __restrict__ bias_comb, float* __restrict__ bias2,
    int* __restrict__ cnt, int* __restrict__ cursor)
{
  const int T0 = 1024, T1 = 4*4*4*64*8, T2 = 10*16*64*8;
  const int TC = 2*NI;
  int total = T0 + T1 + T2 + 256 + 256 + TC + 2;
  for(int t = blockIdx.x*256 + threadIdx.x; t < total; t += gridDim.x*256){
    if(t < T0){
      int which = t>>8, hc = t&255, h = hc>>6, c = hc&63;
      const float *W, *att;
      if(which==0){ W=Wsrc_po;  att=att_src_po; }
      else if(which==1){ W=Wdst_po;  att=att_dst_po; }
      else if(which==2){ W=Wsrc_adj; att=att_src_adj; }
      else { W=Wdst_adj; att=att_dst_adj; }
      float s=0.f;
      for(int j=0;j<64;j++) s += W[c*256 + h*64 + j]*att[h*64+j];
      v4[which*256 + hc] = s;
    } else if(t < T0 + T1){
      int i = t - T0;
      int j = i&7;
      int u4 = i>>3;
      int lane = u4&63;
      int rem = u4>>6;          // h*16 + kt*4 + ct
      int ct = rem&3, kt = (rem>>2)&3, h = rem>>4;
      int r = lane&15, qb = lane>>4;
      int kp = kt*32 + qb*8 + j;
      int n = ct*16 + r;
      float val = (kp<64) ? Wsrc_po[kp*256 + h*64 + n]
                          : Wsrc_adj[(kp-64)*256 + h*64 + n];
      WheadF[i] = f2bf(val);
    } else if(t < T0 + T1 + T2){
      int i = t - (T0+T1);
      int j = i&7;
      int u4 = i>>3;
      int kstep = u4>>10, rem = u4&1023, tile = rem>>6, lane = rem&63;
      int col = tile*16 + (lane&15);
      int k = kstep*32 + (lane>>4)*8 + j;
      B2F[i] = f2bf(b2_val(W_ih, W_hh, col, k));
    } else if(t < T0 + T1 + T2 + 256){
      int m = t - (T0+T1+T2);
      bias_comb[m] = bias_po[m] + bias_adj[m];
    } else if(t < T0 + T1 + T2 + 512){
      int m = t - (T0+T1+T2+256);
      float v;
      if(m<128) v = b_ih[m] + b_hh[m];
      else if(m<192) v = b_ih[m];
      else v = b_hh[m-64];
      bias2[m] = v;
    } else if(t < T0 + T1 + T2 + 512 + TC){
      cnt[t - (T0+T1+T2+512)] = 0;
    } else {
      cursor[t - (T0+T1+T2+512+TC)] = 0;
    }
  }
}

// ---------------- K_ENC: fused lane+int encoders + edge histogram (unchanged) ----------------
__global__ __launch_bounds__(256) void k_enc(
    const float* __restrict__ x_lane, const float* __restrict__ Wl, const float* __restrict__ bl,
    const float* __restrict__ x_int,  const float* __restrict__ Wi, const float* __restrict__ bi,
    const float* __restrict__ v_sp, const float* __restrict__ v_dp,
    const float* __restrict__ v_sa, const float* __restrict__ v_da,
    u16* __restrict__ e_lane, float* __restrict__ a_s_po,
    u16* __restrict__ e_int, float* __restrict__ a_dp, float* __restrict__ a_sa,
    float* __restrict__ a_da,
    const int* __restrict__ dst_po, const int* __restrict__ dst_adj,
    int* __restrict__ cnt)
{
  int t = threadIdx.x;
  int wv = t>>6, l = t&63;
  int g = l&7, m = l>>3;
  int blk = blockIdx.x;
  if(blk < NLB){
    float wreg[12][8], breg[8];
#pragma unroll
    for(int k=0;k<12;k++){
      float4 w0 = *(const float4*)(Wl + k*64 + g*8);
      float4 w1 = *(const float4*)(Wl + k*64 + g*8 + 4);
      wreg[k][0]=w0.x; wreg[k][1]=w0.y; wreg[k][2]=w0.z; wreg[k][3]=w0.w;
      wreg[k][4]=w1.x; wreg[k][5]=w1.y; wreg[k][6]=w1.z; wreg[k][7]=w1.w;
    }
    {
      float4 b0 = *(const float4*)(bl + g*8);
      float4 b1 = *(const float4*)(bl + g*8 + 4);
      breg[0]=b0.x; breg[1]=b0.y; breg[2]=b0.z; breg[3]=b0.w;
      breg[4]=b1.x; breg[5]=b1.y; breg[6]=b1.z; breg[7]=b1.w;
    }
    int rowbase = blk*K1_ROWS + wv*(8*K1_ITER) + m;
    float4 Aa={0,0,0,0}, Ab={0,0,0,0}, Ac={0,0,0,0};
    float4 Ba={0,0,0,0}, Bb={0,0,0,0}, Bc={0,0,0,0};
    if(rowbase < NL){
      const float4* xp = (const float4*)(x_lane + (size_t)rowbase*12);
      Aa = xp[0]; Ab = xp[1]; Ac = xp[2];
    }
    if(rowbase+8 < NL){
      const float4* xp = (const float4*)(x_lane + (size_t)(rowbase+8)*12);
      Ba = xp[0]; Bb = xp[1]; Bc = xp[2];
    }
#pragma unroll
    for(int it=0; it<K1_ITER; it++){
      int row = rowbase + it*8;
      float4 Ca={0,0,0,0}, Cb={0,0,0,0}, Cc={0,0,0,0};
      if(it+2 < K1_ITER && row+16 < NL){
        const float4* xp = (const float4*)(x_lane + (size_t)(row+16)*12);
        Ca = xp[0]; Cb = xp[1]; Cc = xp[2];
      }
      float xv[12];
      xv[0]=Aa.x; xv[1]=Aa.y; xv[2]=Aa.z; xv[3]=Aa.w;
      xv[4]=Ab.x; xv[5]=Ab.y; xv[6]=Ab.z; xv[7]=Ab.w;
      xv[8]=Ac.x; xv[9]=Ac.y; xv[10]=Ac.z; xv[11]=Ac.w;
      float acc[8];
#pragma unroll
      for(int j=0;j<8;j++) acc[j]=breg[j];
#pragma unroll
      for(int k=0;k<12;k++){
        float xk = xv[k];
#pragma unroll
        for(int j=0;j<8;j++) acc[j] += xk*wreg[k][j];
      }
      float e[8];
#pragma unroll
      for(int j=0;j<8;j++) e[j] = fmaxf(acc[j], 0.f);
      float as[4];
#pragma unroll
      for(int h=0;h<4;h++){
        float4 v0 = *(const float4*)(v_sp + h*64 + g*8);
        float4 v1 = *(const float4*)(v_sp + h*64 + g*8 + 4);
        as[h] = e[0]*v0.x + e[1]*v0.y + e[2]*v0.z + e[3]*v0.w
              + e[4]*v1.x + e[5]*v1.y + e[6]*v1.z + e[7]*v1.w;
      }
#pragma unroll
      for(int o=1;o<8;o<<=1){
#pragma unroll
        for(int h=0;h<4;h++) as[h] += __shfl_xor(as[h], o, 64);
      }
      if(row < NL){
        uint4 P;
        P.x = pack2(e[0],e[1]); P.y = pack2(e[2],e[3]);
        P.z = pack2(e[4],e[5]); P.w = pack2(e[6],e[7]);
        ((uint4*)e_lane)[(size_t)row*8 + g] = P;
        if(g==0){
          float4 A; A.x=as[0]; A.y=as[1]; A.z=as[2]; A.w=as[3];
          *(float4*)(a_s_po + (size_t)row*4) = A;
        }
      }
      Aa=Ba; Ab=Bb; Ac=Bc;
      Ba=Ca; Bb=Cb; Bc=Cc;
    }
  } else if(blk < NLB + NIB){
    int b2 = blk - NLB;
    float breg[8];
    {
      float4 b0 = *(const float4*)(bi + g*8);
      float4 b1 = *(const float4*)(bi + g*8 + 4);
      breg[0]=b0.x; breg[1]=b0.y; breg[2]=b0.z; breg[3]=b0.w;
      breg[4]=b1.x; breg[5]=b1.y; breg[6]=b1.z; breg[7]=b1.w;
    }
    int rowbase = b2*K2_ROWS + wv*(8*K2_ITER) + m;
#pragma unroll
    for(int it=0; it<K2_ITER; it++){
      int row = rowbase + it*8;
      float xv[16];
      if(row < NI){
        const float4* xp = (const float4*)(x_int + (size_t)row*16);
#pragma unroll
        for(int q=0;q<4;q++){
          float4 xq = xp[q];
          xv[q*4]=xq.x; xv[q*4+1]=xq.y; xv[q*4+2]=xq.z; xv[q*4+3]=xq.w;
        }
      } else {
#pragma unroll
        for(int k=0;k<16;k++) xv[k]=0.f;
      }
      float acc[8];
#pragma unroll
      for(int j=0;j<8;j++) acc[j]=breg[j];
#pragma unroll
      for(int k=0;k<16;k++){
        float4 w0 = *(const float4*)(Wi + k*64 + g*8);
        float4 w1 = *(const float4*)(Wi + k*64 + g*8 + 4);
        float xk = xv[k];
        acc[0] += xk*w0.x; acc[1] += xk*w0.y; acc[2] += xk*w0.z; acc[3] += xk*w0.w;
        acc[4] += xk*w1.x; acc[5] += xk*w1.y; acc[6] += xk*w1.z; acc[7] += xk*w1.w;
      }
      float e[8];
#pragma unroll
      for(int j=0;j<8;j++) e[j] = fmaxf(acc[j], 0.f);
      float ad[4], sa[4], da[4];
#pragma unroll
      for(int h=0;h<4;h++){
        float4 v0, v1;
        v0 = *(const float4*)(v_dp + h*64 + g*8); v1 = *(const float4*)(v_dp + h*64 + g*8 + 4);
        ad[h] = e[0]*v0.x + e[1]*v0.y + e[2]*v0.z + e[3]*v0.w
              + e[4]*v1.x + e[5]*v1.y + e[6]*v1.z + e[7]*v1.w;
        v0 = *(const float4*)(v_sa + h*64 + g*8); v1 = *(const float4*)(v_sa + h*64 + g*8 + 4);
        sa[h] = e[0]*v0.x + e[1]*v0.y + e[2]*v0.z + e[3]*v0.w
              + e[4]*v1.x + e[5]*v1.y + e[6]*v1.z + e[7]*v1.w;
        v0 = *(const float4*)(v_da + h*64 + g*8); v1 = *(const float4*)(v_da + h*64 + g*8 + 4);
        da[h] = e[0]*v0.x + e[1]*v0.y + e[2]*v0.z + e[3]*v0.w
              + e[4]*v1.x + e[5]*v1.y + e[6]*v1.z + e[7]*v1.w;
      }
#pragma unroll
      for(int o=1;o<8;o<<=1){
#pragma unroll
        for(int h=0;h<4;h++){
          ad[h] += __shfl_xor(ad[h], o, 64);
          sa[h] += __shfl_xor(sa[h], o, 64);
          da[h] += __shfl_xor(da[h], o, 64);
        }
      }
      if(row < NI){
        uint4 P;
        P.x = pack2(e[0],e[1]); P.y = pack2(e[2],e[3]);
        P.z = pack2(e[4],e[5]); P.w = pack2(e[6],e[7]);
        ((uint4*)e_int)[(size_t)row*8 + g] = P;
        if(g==0){
          float4 A;
          A.x=ad[0]; A.y=ad[1]; A.z=ad[2]; A.w=ad[3]; *(float4*)(a_dp + (size_t)row*4) = A;
          A.x=sa[0]; A.y=sa[1]; A.z=sa[2]; A.w=sa[3]; *(float4*)(a_sa + (size_t)row*4) = A;
          A.x=da[0]; A.y=da[1]; A.z=da[2]; A.w=da[3]; *(float4*)(a_da + (size_t)row*4) = A;
        }
      }
    }
  } else {
    int i = (blk - NLB - NIB)*256 + t;
    if(i < EPO) atomicAdd(&cnt[dst_po[i]], 1);
    else if(i < EPO+EADJ) atomicAdd(&cnt[NI + dst_adj[i-EPO]], 1);
  }
}

// ---------------- K4: single-kernel order-free scan ----------------
__global__ __launch_bounds__(256) void k4_scan(
    const int* __restrict__ cnt, int* __restrict__ offA, int* __restrict__ cur,
    int* __restrict__ cursor)
{
  int y = blockIdx.y;
  int wid = threadIdx.x>>6, lane = threadIdx.x&63;
  int base_i = (blockIdx.x*4 + wid)*256;
  int v[4], inc[4], ctot[4];
#pragma unroll
  for(int c=0;c<4;c++){
    int i = base_i + c*64 + lane;
    v[c] = (i<NI) ? cnt[(size_t)y*NI+i] : 0;
    int x = v[c];
#pragma unroll
    for(int o=1;o<64;o<<=1){
      int tt = __shfl_up(x,o,64);
      if(lane>=o) x += tt;
    }
    inc[c] = x;
    ctot[c] = __shfl(x, 63, 64);
  }
  int cpre[4];
  cpre[0]=0;
  cpre[1]=ctot[0];
  cpre[2]=cpre[1]+ctot[1];
  cpre[3]=cpre[2]+ctot[2];
  int wtot = cpre[3]+ctot[3];
  int base = 0;
  if(lane==0) base = atomicAdd(&cursor[y], wtot);
  base = __shfl(base, 0, 64);
#pragma unroll
  for(int c=0;c<4;c++){
    int i = base_i + c*64 + lane;
    if(i<NI){
      int o = base + cpre[c] + inc[c] - v[c];
      offA[(size_t)y*NI+i] = o;
      cur[(size_t)y*NI+i]  = o;
    }
  }
}

// ---------------- K5 v3: pure CSR scatter (no exp, no gathers) ----------------
__global__ __launch_bounds__(256) void k5_scatter(
    const int* __restrict__ src_po, const int* __restrict__ dst_po,
    const int* __restrict__ src_adj, const int* __restrict__ dst_adj,
    int* __restrict__ cur, int* __restrict__ csr_po, int* __restrict__ csr_adj)
{
  int i = blockIdx.x*256 + threadIdx.x;
  if(i < EPO){
    int s = src_po[i];
    int d = dst_po[i];
    int p = atomicAdd(&cur[d],1);
    csr_po[p] = s;
  } else if(i < EPO+EADJ){
    int e = i-EPO;
    int s = src_adj[e];
    int d = dst_adj[e];
    int p = atomicAdd(&cur[NI+d],1);
    csr_adj[p] = s;
  }
}

// ---------------- K6 v4: in-kernel exp weights (lane-owned) + shuffle broadcast ----------------
__device__ __forceinline__ void agg_rel(
    int beg, int n, int lane,
    const int* __restrict__ csr, const float* __restrict__ a_s, float4 ad,
    const u16* __restrict__ emat, u16* __restrict__ aggrow)
{
  float l0=0,l1=0,l2=0,l3=0;
  float c0=0,c1=0,c2=0,c3=0;
  for(int base=0;base<n;base+=64){
    int m = n-base; if(m>64) m=64;
    int sv_ = (lane<m) ? csr[beg+base+lane] : 0;
    float4 as = {0,0,0,0};
    if(lane<m) as = *(const float4*)(a_s + (size_t)sv_*4);
    float pe0,pe1,pe2,pe3;
    {
      float x;
      x = as.x+ad.x; pe0 = __expf(x>0.f?x:0.2f*x);
      x = as.y+ad.y; pe1 = __expf(x>0.f?x:0.2f*x);
      x = as.z+ad.z; pe2 = __expf(x>0.f?x:0.2f*x);
      x = as.w+ad.w; pe3 = __expf(x>0.f?x:0.2f*x);
    }
    int t2=0;
    for(; t2+3<m; t2+=4){
      int s0 = __shfl(sv_, t2,   64);
      int s1 = __shfl(sv_, t2+1, 64);
      int s2 = __shfl(sv_, t2+2, 64);
      int s3 = __shfl(sv_, t2+3, 64);
      float e0 = bf2f(emat[(size_t)s0*64+lane]);
      float e1 = bf2f(emat[(size_t)s1*64+lane]);
      float e2 = bf2f(emat[(size_t)s2*64+lane]);
      float e3 = bf2f(emat[(size_t)s3*64+lane]);
      float w00=__shfl(pe0,t2,64),   w01=__shfl(pe1,t2,64),   w02=__shfl(pe2,t2,64),   w03=__shfl(pe3,t2,64);
      float w10=__shfl(pe0,t2+1,64), w11=__shfl(pe1,t2+1,64), w12=__shfl(pe2,t2+1,64), w13=__shfl(pe3,t2+1,64);
      float w20=__shfl(pe0,t2+2,64), w21=__shfl(pe1,t2+2,64), w22=__shfl(pe2,t2+2,64), w23=__shfl(pe3,t2+2,64);
      float w30=__shfl(pe0,t2+3,64), w31=__shfl(pe1,t2+3,64), w32=__shfl(pe2,t2+3,64), w33=__shfl(pe3,t2+3,64);
      c0 += w00*e0; c1 += w01*e0; c2 += w02*e0; c3 += w03*e0;
      l0 += w00;    l1 += w01;    l2 += w02;    l3 += w03;
      c0 += w10*e1; c1 += w11*e1; c2 += w12*e1; c3 += w13*e1;
      l0 += w10;    l1 += w11;    l2 += w12;    l3 += w13;
      c0 += w20*e2; c1 += w21*e2; c2 += w22*e2; c3 += w23*e2;
      l0 += w20;    l1 += w21;    l2 += w22;    l3 += w23;
      c0 += w30*e3; c1 += w31*e3; c2 += w32*e3; c3 += w33*e3;
      l0 += w30;    l1 += w31;    l2 += w32;    l3 += w33;
    }
    for(; t2<m; t2++){
      int s0 = __shfl(sv_, t2, 64);
      float e0 = bf2f(emat[(size_t)s0*64+lane]);
      float w0=__shfl(pe0,t2,64), w1=__shfl(pe1,t2,64), w2=__shfl(pe2,t2,64), w3=__shfl(pe3,t2,64);
      c0 += w0*e0; c1 += w1*e0; c2 += w2*e0; c3 += w3*e0;
      l0 += w0;    l1 += w1;    l2 += w2;    l3 += w3;
    }
  }
  aggrow[lane]       = f2bf(n>0 ? c0/l0 : 0.f);
  aggrow[64+lane]    = f2bf(n>0 ? c1/l1 : 0.f);
  aggrow[128+lane]   = f2bf(n>0 ? c2/l2 : 0.f);
  aggrow[192+lane]   = f2bf(n>0 ? c3/l3 : 0.f);
}

__global__ __launch_bounds__(512) void k6_agg(
    const int* __restrict__ off, const int* __restrict__ cnt,
    const int* __restrict__ csr_po, const int* __restrict__ csr_adj,
    const float* __restrict__ a_s_po, const float* __restrict__ a_d_po,
    const float* __restrict__ a_s_adj, const float* __restrict__ a_d_adj,
    const u16* __restrict__ e_lane, const u16* __restrict__ e_int,
    u16* __restrict__ agg)
{
  int wave=threadIdx.x>>6, lane=threadIdx.x&63;
  int d = blockIdx.x*4 + (wave&3);
  if(d>=NI) return;
  if(wave < 4){
    float4 ad = *(const float4*)(a_d_po + (size_t)d*4);
    agg_rel(off[d],    cnt[d],    lane, csr_po,  a_s_po,  ad, e_lane, agg + (size_t)d*512);
  } else {
    float4 ad = *(const float4*)(a_d_adj + (size_t)d*4);
    agg_rel(off[NI+d], cnt[NI+d], lane, csr_adj, a_s_adj, ad, e_int,  agg + (size_t)d*512 + 256);
  }
}

// ---------------- K8 v3: A staged wave-private, B fragment-direct (unchanged from R15) ----------------
__global__ __launch_bounds__(256) void k8_fused(
    const u16* __restrict__ agg, const uint4* __restrict__ WheadF,
    const float* __restrict__ bias_comb,
    const uint4* __restrict__ B2F, const float* __restrict__ bias2,
    const float* __restrict__ h0,
    const float* __restrict__ Wpi, const float* __restrict__ bpi,
    const float* __restrict__ Wv, const float* __restrict__ bvp,
    float* __restrict__ out)
{
  __shared__ u16 As[64][136];
  __shared__ u16 interT[64][264];
  int t=threadIdx.x, w=t>>6, lane=t&63;
  int r = lane&15, q = lane>>4;
  int row0 = blockIdx.x*64;

  for(int h=0;h<4;h++){
#pragma unroll
    for(int it=0; it<4; it++){
      int lrow = it*4 + q;
      int grow = row0 + w*16 + lrow;
      int arc = grow < NI ? grow : NI-1;
      int u4p = lane&15;
      int co = (u4p<8) ? (h*64 + u4p*8) : (256 + h*64 + (u4p-8)*8);
      uint4 v = *(const uint4*)(agg + (size_t)arc*512 + co);
      *(uint4*)&As[w*16 + lrow][u4p*8] = v;
    }
    __syncthreads();
    bf16x8 af[4];
#pragma unroll
    for(int kt=0;kt<4;kt++)
      af[kt] = *(const bf16x8*)&As[w*16 + r][q*8 + kt*32];
    const uint4* BF = WheadF + (size_t)h*16*64;
#pragma unroll
    for(int ct=0; ct<4; ct++){
      f32x4 facc = {0,0,0,0};
#pragma unroll
      for(int kt=0; kt<4; kt++){
        uint4 bu = BF[(kt*4 + ct)*64 + lane];
        bf16x8 bfr; *(uint4*)&bfr = bu;
        facc = __builtin_amdgcn_mfma_f32_16x16x32_bf16(af[kt], bfr, facc, 0,0,0);
      }
      int col = h*64 + ct*16 + r;
      float bcol = bias_comb[col];
#pragma unroll
      for(int rr=0; rr<4; rr++)
        interT[w*16 + q*4 + rr][col] = f2bf(fmaxf(facc[rr]+bcol, 0.f));
    }
  }
  __syncthreads();

  int arowl = w*16 + r;
  int arow  = row0 + arowl;
  int arc = arow < NI ? arow : NI-1;
  const float* h0r = h0 + (size_t)arc*64 + q*8;
  f32x4 acc[16];
#pragma unroll
  for(int i=0;i<16;i++) acc[i] = (f32x4){0,0,0,0};
#pragma unroll
  for(int ks=0; ks<10; ks++){
    bf16x8 af;
    if(ks < 8){
      af = *(const bf16x8*)&interT[arowl][ks*32 + q*8];
    } else {
      const float* hp = h0r + (ks-8)*32;
      float4 f0 = *(const float4*)(hp);
      float4 f1 = *(const float4*)(hp+4);
      uint4 P;
      P.x = pack2(f0.x,f0.y); P.y = pack2(f0.z,f0.w);
      P.z = pack2(f1.x,f1.y); P.w = pack2(f1.z,f1.w);
      *(uint4*)&af = P;
    }
    const uint4* bp = B2F + ks*1024 + lane;
#pragma unroll
    for(int tt=0;tt<16;tt++){
      uint4 bu = bp[tt*64];
      bf16x8 bfr; *(uint4*)&bfr = bu;
      acc[tt] = __builtin_amdgcn_mfma_f32_16x16x32_bf16(af, bfr, acc[tt], 0,0,0);
    }
  }
  float pk[4][8];
  float pv[4];
#pragma unroll
  for(int rr=0;rr<4;rr++){
    pv[rr]=0.f;
#pragma unroll
    for(int j=0;j<8;j++) pk[rr][j]=0.f;
  }
  int rbase = row0 + w*16 + q*4;
#pragma unroll
  for(int t2=0;t2<4;t2++){
    int c = t2*16 + r;
    float b0 = bias2[c], b1 = bias2[64+c], b2 = bias2[128+c], b3 = bias2[192+c];
    float wp[8];
#pragma unroll
    for(int j=0;j<8;j++) wp[j] = Wpi[c*8+j];
    float wv = Wv[c];
#pragma unroll
    for(int rr=0;rr<4;rr++){
      int row = rbase + rr;
      float g0 = acc[t2][rr]    + b0;
      float g1 = acc[t2+4][rr]  + b1;
      float g2 = acc[t2+8][rr]  + b2;
      float g3 = acc[t2+12][rr] + b3;
      float h0v = (row < NI) ? h0[(size_t)row*64 + c] : 0.f;
      float rg = 1.f/(1.f+__expf(-g0));
      float zg = 1.f/(1.f+__expf(-g1));
      float e2 = __expf(2.f*(g2 + rg*g3));
      float ng = 1.f - 2.f/(e2+1.f);
      float hh = (1.f-zg)*ng + zg*h0v;
      if(row < NI) out[450000 + (size_t)row*64 + c] = hh;
#pragma unroll
      for(int j=0;j<8;j++) pk[rr][j] += hh*wp[j];
      pv[rr] += hh*wv;
    }
  }
#pragma unroll
  for(int o=1;o<16;o<<=1){
#pragma unroll
    for(int rr=0;rr<4;rr++){
#pragma unroll
      for(int j=0;j<8;j++) pk[rr][j] += __shfl_xor(pk[rr][j], o, 64);
      pv[rr] += __shfl_xor(pv[rr], o, 64);
    }
  }
  if(r==0){
#pragma unroll
    for(int rr=0;rr<4;rr++){
      int row = rbase + rr;
      if(row < NI){
#pragma unroll
        for(int j=0;j<8;j++) out[(size_t)row*8 + j] = pk[rr][j] + bpi[j];
        out[400000 + row] = pv[rr] + bvp[0];
      }
    }
  }
}

extern "C" void kernel_launch(void* const* d_in, const int* in_sizes, int n_in,
                              void* d_out, int out_size, void* d_ws, size_t ws_size,
                              hipStream_t stream) {
  const float* x_int      = (const float*)d_in[0];
  const float* x_lane     = (const float*)d_in[1];
  const float* h0         = (const float*)d_in[2];
  const float* enc_int_W  = (const float*)d_in[3];
  const float* enc_int_b  = (const float*)d_in[4];
  const float* enc_lane_W = (const float*)d_in[5];
  const float* enc_lane_b = (const float*)d_in[6];
  const float* Wsrc_po    = (const float*)d_in[7];
  const float* Wdst_po    = (const float*)d_in[8];
  const float* att_src_po = (const float*)d_in[9];
  const float* att_dst_po = (const float*)d_in[10];
  const float* bias_po    = (const float*)d_in[11];
  const float* Wsrc_adj   = (const float*)d_in[12];
  const float* Wdst_adj   = (const float*)d_in[13];
  const float* att_src_adj= (const float*)d_in[14];
  const float* att_dst_adj= (const float*)d_in[15];
  const float* bias_adj   = (const float*)d_in[16];
  const float* gru_W_ih   = (const float*)d_in[17];
  const float* gru_W_hh   = (const float*)d_in[18];
  const float* gru_b_ih   = (const float*)d_in[19];
  const float* gru_b_hh   = (const float*)d_in[20];
  const float* W_pi       = (const float*)d_in[21];
  const float* b_pi       = (const float*)d_in[22];
  const float* W_v        = (const float*)d_in[23];
  const float* b_v        = (const float*)d_in[24];
  const int* src_po  = (const int*)d_in[25];
  const int* dst_po  = (const int*)d_in[26];
  const int* src_adj = (const int*)d_in[27];
  const int* dst_adj = (const int*)d_in[28];
  float* out = (float*)d_out;

  char* w = (char*)d_ws;
  size_t ofs = 0;
  auto alloc = [&](size_t bytes)->char*{
    char* p = w + ofs;
    ofs = (ofs + bytes + 255) & ~(size_t)255;
    return p;
  };
  u16*  e_lane   = (u16*)alloc((size_t)NL*64*2);
  u16*  e_int    = (u16*)alloc((size_t)NI*64*2);
  float* a_s_po  = (float*)alloc((size_t)NL*4*4);
  float* a_d_po  = (float*)alloc((size_t)NI*4*4);
  float* a_s_adj = (float*)alloc((size_t)NI*4*4);
  float* a_d_adj = (float*)alloc((size_t)NI*4*4);
  int*  cnt      = (int*)alloc((size_t)2*NI*4);
  int*  offA     = (int*)alloc((size_t)2*NI*4);
  int*  cur      = (int*)alloc((size_t)2*NI*4);
  int*  csr_po   = (int*)alloc((size_t)EPO*4);
  int*  csr_adj  = (int*)alloc((size_t)EADJ*4);
  int*  cursor   = (int*)alloc(2*4);
  u16*  agg      = (u16*)alloc((size_t)NI*512*2);
  u16*  WheadF   = (u16*)alloc(4*4*4*64*8*2);
  u16*  B2F      = (u16*)alloc(10*16*64*8*2);
  float* v4      = (float*)alloc(4*256*4);
  float* bias_comb = (float*)alloc(256*4);
  float* bias2   = (float*)alloc(256*4);
  (void)ws_size; (void)n_in; (void)in_sizes; (void)out_size;

  k0_prep<<<256, 256, 0, stream>>>(
      Wsrc_po, att_src_po, Wdst_po, att_dst_po,
      Wsrc_adj, att_src_adj, Wdst_adj, att_dst_adj,
      gru_W_ih, gru_W_hh, bias_po, bias_adj, gru_b_ih, gru_b_hh,
      v4, WheadF, B2F, bias_comb, bias2, cnt, cursor);
  k_enc<<<NLB+NIB+NHB, 256, 0, stream>>>(
      x_lane, enc_lane_W, enc_lane_b,
      x_int, enc_int_W, enc_int_b,
      v4 + 0, v4 + 256, v4 + 512, v4 + 768,
      e_lane, a_s_po, e_int, a_d_po, a_s_adj, a_d_adj,
      dst_po, dst_adj, cnt);
  k4_scan<<<dim3((NI+1023)/1024, 2), 256, 0, stream>>>(cnt, offA, cur, cursor);
  k5_scatter<<<(EPO+EADJ+255)/256, 256, 0, stream>>>(src_po, dst_po, src_adj, dst_adj,
      cur, csr_po, csr_adj);
  k6_agg<<<(NI+3)/4, 512, 0, stream>>>(offA, cnt, csr_po, csr_adj,
      a_s_po, a_d_po, a_s_adj, a_d_adj, e_lane, e_int, agg);
  k8_fused<<<(NI+63)/64, 256, 0, stream>>>(agg, (const uint4*)WheadF, bias_comb,
      (const uint4*)B2F, bias2, h0, W_pi, b_pi, W_v, b_v, out);
}

// Round 17
// 335.739 us; speedup vs baseline: 1.2055x; 1.0326x over previous
//
#include <hip/hip_runtime.h>

#define NI 50000
#define NL 400000
#define EPO 400000
#define EADJ 200000

// encoder tiling
#define K1_ITER 8
#define K2_ITER 4
#define K1_ROWS (32*K1_ITER)   // 256 rows/block
#define K2_ROWS (32*K2_ITER)   // 128 rows/block
#define NLB ((NL + K1_ROWS - 1)/K1_ROWS)   // 1563
#define NIB ((NI + K2_ROWS - 1)/K2_ROWS)   // 391
#define NHB ((EPO + EADJ + 255)/256)       // 2344 histogram blocks

typedef unsigned int u32;
typedef unsigned short u16;
typedef short bf16x8 __attribute__((ext_vector_type(8)));
typedef float f32x4 __attribute__((ext_vector_type(4)));

__device__ __forceinline__ float bf2f(u16 h){ return __uint_as_float(((u32)h)<<16); }
__device__ __forceinline__ u16 f2bf(float f){
  u32 u = __float_as_uint(f);
  u += 0x7FFFu + ((u>>16)&1u);
  return (u16)(u>>16);
}
__device__ __forceinline__ u32 pack2(float a, float b){
  return (u32)f2bf(a) | ((u32)f2bf(b)<<16);
}

// GRU combined weight value: maps [inter(256) | h0(64)] -> [r_sum, z_sum, i_n, h_n]
__device__ __forceinline__ float b2_val(
    const float* __restrict__ W_ih, const float* __restrict__ W_hh, int m, int k)
{
  if(k < 256){ return (m<192) ? W_ih[m*256+k] : 0.f; }
  int kk = k-256;
  if(m<128) return W_hh[m*64+kk];
  if(m>=192) return W_hh[(m-64)*64+kk];
  return 0.f;
}

// ---------------- K0: weight prep + cnt/cursor zeroing ----------------
__global__ __launch_bounds__(256) void k0_prep(
    const float* __restrict__ Wsrc_po, const float* __restrict__ att_src_po,
    const float* __restrict__ Wdst_po, const float* __restrict__ att_dst_po,
    const float* __restrict__ Wsrc_adj, const float* __restrict__ att_src_adj,
    const float* __restrict__ Wdst_adj, const float* __restrict__ att_dst_adj,
    const float* __restrict__ W_ih, const float* __restrict__ W_hh,
    const float* __restrict__ bias_po, const float* __restrict__ bias_adj,
    const float* __restrict__ b_ih, const float* __restrict__ b_hh,
    float* __restrict__ v4, u16* __restrict__ WheadF, u16* __restrict__ B2F,
    float* __restrict__ bias_comb, float* __restrict__ bias2,
    int* __restrict__ cnt, int* __restrict__ cursor)
{
  const int T0 = 1024, T1 = 4*4*4*64*8, T2 = 10*16*64*8;
  const int TC = 2*NI;
  int total = T0 + T1 + T2 + 256 + 256 + TC + 2;
  for(int t = blockIdx.x*256 + threadIdx.x; t < total; t += gridDim.x*256){
    if(t < T0){
      int which = t>>8, hc = t&255, h = hc>>6, c = hc&63;
      const float *W, *att;
      if(which==0){ W=Wsrc_po;  att=att_src_po; }
      else if(which==1){ W=Wdst_po;  att=att_dst_po; }
      else if(which==2){ W=Wsrc_adj; att=att_src_adj; }
      else { W=Wdst_adj; att=att_dst_adj; }
      float s=0.f;
      for(int j=0;j<64;j++) s += W[c*256 + h*64 + j]*att[h*64+j];
      v4[which*256 + hc] = s;
    } else if(t < T0 + T1){
      int i = t - T0;
      int j = i&7;
      int u4 = i>>3;
      int lane = u4&63;
      int rem = u4>>6;          // h*16 + kt*4 + ct
      int ct = rem&3, kt = (rem>>2)&3, h = rem>>4;
      int r = lane&15, qb = lane>>4;
      int kp = kt*32 + qb*8 + j;
      int n = ct*16 + r;
      float val = (kp<64) ? Wsrc_po[kp*256 + h*64 + n]
                          : Wsrc_adj[(kp-64)*256 + h*64 + n];
      WheadF[i] = f2bf(val);
    } else if(t < T0 + T1 + T2){
      int i = t - (T0+T1);
      int j = i&7;
      int u4 = i>>3;
      int kstep = u4>>10, rem = u4&1023, tile = rem>>6, lane = rem&63;
      int col = tile*16 + (lane&15);
      int k = kstep*32 + (lane>>4)*8 + j;
      B2F[i] = f2bf(b2_val(W_ih, W_hh, col, k));
    } else if(t < T0 + T1 + T2 + 256){
      int m = t - (T0+T1+T2);
      bias_comb[m] = bias_po[m] + bias_adj[m];
    } else if(t < T0 + T1 + T2 + 512){
      int m = t - (T0+T1+T2+256);
      float v;
      if(m<128) v = b_ih[m] + b_hh[m];
      else if(m<192) v = b_ih[m];
      else v = b_hh[m-64];
      bias2[m] = v;
    } else if(t < T0 + T1 + T2 + 512 + TC){
      cnt[t - (T0+T1+T2+512)] = 0;
    } else {
      cursor[t - (T0+T1+T2+512+TC)] = 0;
    }
  }
}

// ---------------- K_ENC: fused lane+int encoders + edge histogram ----------------
__global__ __launch_bounds__(256) void k_enc(
    const float* __restrict__ x_lane, const float* __restrict__ Wl, const float* __restrict__ bl,
    const float* __restrict__ x_int,  const float* __restrict__ Wi, const float* __restrict__ bi,
    const float* __restrict__ v_sp, const float* __restrict__ v_dp,
    const float* __restrict__ v_sa, const float* __restrict__ v_da,
    u16* __restrict__ e_lane, float* __restrict__ a_s_po,
    u16* __restrict__ e_int, float* __restrict__ a_dp, float* __restrict__ a_sa,
    float* __restrict__ a_da,
    const int* __restrict__ dst_po, const int* __restrict__ dst_adj,
    int* __restrict__ cnt)
{
  int t = threadIdx.x;
  int wv = t>>6, l = t&63;
  int g = l&7, m = l>>3;
  int blk = blockIdx.x;
  if(blk < NLB){
    float wreg[12][8], breg[8], vreg[4][8];
#pragma unroll
    for(int k=0;k<12;k++){
      float4 w0 = *(const float4*)(Wl + k*64 + g*8);
      float4 w1 = *(const float4*)(Wl + k*64 + g*8 + 4);
      wreg[k][0]=w0.x; wreg[k][1]=w0.y; wreg[k][2]=w0.z; wreg[k][3]=w0.w;
      wreg[k][4]=w1.x; wreg[k][5]=w1.y; wreg[k][6]=w1.z; wreg[k][7]=w1.w;
    }
    {
      float4 b0 = *(const float4*)(bl + g*8);
      float4 b1 = *(const float4*)(bl + g*8 + 4);
      breg[0]=b0.x; breg[1]=b0.y; breg[2]=b0.z; breg[3]=b0.w;
      breg[4]=b1.x; breg[5]=b1.y; breg[6]=b1.z; breg[7]=b1.w;
    }
#pragma unroll
    for(int h=0;h<4;h++){
      float4 v0 = *(const float4*)(v_sp + h*64 + g*8);
      float4 v1 = *(const float4*)(v_sp + h*64 + g*8 + 4);
      vreg[h][0]=v0.x; vreg[h][1]=v0.y; vreg[h][2]=v0.z; vreg[h][3]=v0.w;
      vreg[h][4]=v1.x; vreg[h][5]=v1.y; vreg[h][6]=v1.z; vreg[h][7]=v1.w;
    }
    int rowbase = blk*K1_ROWS + wv*(8*K1_ITER) + m;
    float4 Aa={0,0,0,0}, Ab={0,0,0,0}, Ac={0,0,0,0};
    float4 Ba={0,0,0,0}, Bb={0,0,0,0}, Bc={0,0,0,0};
    if(rowbase < NL){
      const float4* xp = (const float4*)(x_lane + (size_t)rowbase*12);
      Aa = xp[0]; Ab = xp[1]; Ac = xp[2];
    }
    if(rowbase+8 < NL){
      const float4* xp = (const float4*)(x_lane + (size_t)(rowbase+8)*12);
      Ba = xp[0]; Bb = xp[1]; Bc = xp[2];
    }
#pragma unroll
    for(int it=0; it<K1_ITER; it++){
      int row = rowbase + it*8;
      float4 Ca={0,0,0,0}, Cb={0,0,0,0}, Cc={0,0,0,0};
      if(it+2 < K1_ITER && row+16 < NL){
        const float4* xp = (const float4*)(x_lane + (size_t)(row+16)*12);
        Ca = xp[0]; Cb = xp[1]; Cc = xp[2];
      }
      float xv[12];
      xv[0]=Aa.x; xv[1]=Aa.y; xv[2]=Aa.z; xv[3]=Aa.w;
      xv[4]=Ab.x; xv[5]=Ab.y; xv[6]=Ab.z; xv[7]=Ab.w;
      xv[8]=Ac.x; xv[9]=Ac.y; xv[10]=Ac.z; xv[11]=Ac.w;
      float acc[8];
#pragma unroll
      for(int j=0;j<8;j++) acc[j]=breg[j];
#pragma unroll
      for(int k=0;k<12;k++){
        float xk = xv[k];
#pragma unroll
        for(int j=0;j<8;j++) acc[j] += xk*wreg[k][j];
      }
      float e[8];
#pragma unroll
      for(int j=0;j<8;j++) e[j] = fmaxf(acc[j], 0.f);
      float as[4];
#pragma unroll
      for(int h=0;h<4;h++){
        as[h] = e[0]*vreg[h][0] + e[1]*vreg[h][1] + e[2]*vreg[h][2] + e[3]*vreg[h][3]
              + e[4]*vreg[h][4] + e[5]*vreg[h][5] + e[6]*vreg[h][6] + e[7]*vreg[h][7];
      }
#pragma unroll
      for(int o=1;o<8;o<<=1){
#pragma unroll
        for(int h=0;h<4;h++) as[h] += __shfl_xor(as[h], o, 64);
      }
      if(row < NL){
        uint4 P;
        P.x = pack2(e[0],e[1]); P.y = pack2(e[2],e[3]);
        P.z = pack2(e[4],e[5]); P.w = pack2(e[6],e[7]);
        ((uint4*)e_lane)[(size_t)row*8 + g] = P;
        if(g==0){
          float4 A; A.x=as[0]; A.y=as[1]; A.z=as[2]; A.w=as[3];
          *(float4*)(a_s_po + (size_t)row*4) = A;
        }
      }
      Aa=Ba; Ab=Bb; Ac=Bc;
      Ba=Ca; Bb=Cb; Bc=Cc;
    }
  } else if(blk < NLB + NIB){
    int b2 = blk - NLB;
    float breg[8];
    {
      float4 b0 = *(const float4*)(bi + g*8);
      float4 b1 = *(const float4*)(bi + g*8 + 4);
      breg[0]=b0.x; breg[1]=b0.y; breg[2]=b0.z; breg[3]=b0.w;
      breg[4]=b1.x; breg[5]=b1.y; breg[6]=b1.z; breg[7]=b1.w;
    }
    int rowbase = b2*K2_ROWS + wv*(8*K2_ITER) + m;
#pragma unroll
    for(int it=0; it<K2_ITER; it++){
      int row = rowbase + it*8;
      float xv[16];
      if(row < NI){
        const float4* xp = (const float4*)(x_int + (size_t)row*16);
#pragma unroll
        for(int q=0;q<4;q++){
          float4 xq = xp[q];
          xv[q*4]=xq.x; xv[q*4+1]=xq.y; xv[q*4+2]=xq.z; xv[q*4+3]=xq.w;
        }
      } else {
#pragma unroll
        for(int k=0;k<16;k++) xv[k]=0.f;
      }
      float acc[8];
#pragma unroll
      for(int j=0;j<8;j++) acc[j]=breg[j];
#pragma unroll
      for(int k=0;k<16;k++){
        float4 w0 = *(const float4*)(Wi + k*64 + g*8);
        float4 w1 = *(const float4*)(Wi + k*64 + g*8 + 4);
        float xk = xv[k];
        acc[0] += xk*w0.x; acc[1] += xk*w0.y; acc[2] += xk*w0.z; acc[3] += xk*w0.w;
        acc[4] += xk*w1.x; acc[5] += xk*w1.y; acc[6] += xk*w1.z; acc[7] += xk*w1.w;
      }
      float e[8];
#pragma unroll
      for(int j=0;j<8;j++) e[j] = fmaxf(acc[j], 0.f);
      float ad[4], sa[4], da[4];
#pragma unroll
      for(int h=0;h<4;h++){
        float4 v0, v1;
        v0 = *(const float4*)(v_dp + h*64 + g*8); v1 = *(const float4*)(v_dp + h*64 + g*8 + 4);
        ad[h] = e[0]*v0.x + e[1]*v0.y + e[2]*v0.z + e[3]*v0.w
              + e[4]*v1.x + e[5]*v1.y + e[6]*v1.z + e[7]*v1.w;
        v0 = *(const float4*)(v_sa + h*64 + g*8); v1 = *(const float4*)(v_sa + h*64 + g*8 + 4);
        sa[h] = e[0]*v0.x + e[1]*v0.y + e[2]*v0.z + e[3]*v0.w
              + e[4]*v1.x + e[5]*v1.y + e[6]*v1.z + e[7]*v1.w;
        v0 = *(const float4*)(v_da + h*64 + g*8); v1 = *(const float4*)(v_da + h*64 + g*8 + 4);
        da[h] = e[0]*v0.x + e[1]*v0.y + e[2]*v0.z + e[3]*v0.w
              + e[4]*v1.x + e[5]*v1.y + e[6]*v1.z + e[7]*v1.w;
      }
#pragma unroll
      for(int o=1;o<8;o<<=1){
#pragma unroll
        for(int h=0;h<4;h++){
          ad[h] += __shfl_xor(ad[h], o, 64);
          sa[h] += __shfl_xor(sa[h], o, 64);
          da[h] += __shfl_xor(da[h], o, 64);
        }
      }
      if(row < NI){
        uint4 P;
        P.x = pack2(e[0],e[1]); P.y = pack2(e[2],e[3]);
        P.z = pack2(e[4],e[5]); P.w = pack2(e[6],e[7]);
        ((uint4*)e_int)[(size_t)row*8 + g] = P;
        if(g==0){
          float4 A;
          A.x=ad[0]; A.y=ad[1]; A.z=ad[2]; A.w=ad[3]; *(float4*)(a_dp + (size_t)row*4) = A;
          A.x=sa[0]; A.y=sa[1]; A.z=sa[2]; A.w=sa[3]; *(float4*)(a_sa + (size_t)row*4) = A;
          A.x=da[0]; A.y=da[1]; A.z=da[2]; A.w=da[3]; *(float4*)(a_da + (size_t)row*4) = A;
        }
      }
    }
  } else {
    int i = (blk - NLB - NIB)*256 + t;
    if(i < EPO) atomicAdd(&cnt[dst_po[i]], 1);
    else if(i < EPO+EADJ) atomicAdd(&cnt[NI + dst_adj[i-EPO]], 1);
  }
}

// ---------------- K4: single-kernel order-free scan ----------------
__global__ __launch_bounds__(256) void k4_scan(
    const int* __restrict__ cnt, int* __restrict__ offA, int* __restrict__ cur,
    int* __restrict__ cursor)
{
  int y = blockIdx.y;
  int wid = threadIdx.x>>6, lane = threadIdx.x&63;
  int base_i = (blockIdx.x*4 + wid)*256;
  int v[4], inc[4], ctot[4];
#pragma unroll
  for(int c=0;c<4;c++){
    int i = base_i + c*64 + lane;
    v[c] = (i<NI) ? cnt[(size_t)y*NI+i] : 0;
    int x = v[c];
#pragma unroll
    for(int o=1;o<64;o<<=1){
      int tt = __shfl_up(x,o,64);
      if(lane>=o) x += tt;
    }
    inc[c] = x;
    ctot[c] = __shfl(x, 63, 64);
  }
  int cpre[4];
  cpre[0]=0;
  cpre[1]=ctot[0];
  cpre[2]=cpre[1]+ctot[1];
  cpre[3]=cpre[2]+ctot[2];
  int wtot = cpre[3]+ctot[3];
  int base = 0;
  if(lane==0) base = atomicAdd(&cursor[y], wtot);
  base = __shfl(base, 0, 64);
#pragma unroll
  for(int c=0;c<4;c++){
    int i = base_i + c*64 + lane;
    if(i<NI){
      int o = base + cpre[c] + inc[c] - v[c];
      offA[(size_t)y*NI+i] = o;
      cur[(size_t)y*NI+i]  = o;
    }
  }
}

// ---------------- K5: pure CSR scatter ----------------
__global__ __launch_bounds__(256) void k5_scatter(
    const int* __restrict__ src_po, const int* __restrict__ dst_po,
    const int* __restrict__ src_adj, const int* __restrict__ dst_adj,
    int* __restrict__ cur, int* __restrict__ csr_po, int* __restrict__ csr_adj)
{
  int i = blockIdx.x*256 + threadIdx.x;
  if(i < EPO){
    int s = src_po[i];
    int d = dst_po[i];
    int p = atomicAdd(&cur[d],1);
    csr_po[p] = s;
  } else if(i < EPO+EADJ){
    int e = i-EPO;
    int s = src_adj[e];
    int d = dst_adj[e];
    int p = atomicAdd(&cur[NI+d],1);
    csr_adj[p] = s;
  }
}

// ---------------- K6: in-kernel exp weights (lane-owned) + shuffle broadcast ----------------
__device__ __forceinline__ void agg_rel(
    int beg, int n, int lane,
    const int* __restrict__ csr, const float* __restrict__ a_s, float4 ad,
    const u16* __restrict__ emat, u16* __restrict__ aggrow)
{
  float l0=0,l1=0,l2=0,l3=0;
  float c0=0,c1=0,c2=0,c3=0;
  for(int base=0;base<n;base+=64){
    int m = n-base; if(m>64) m=64;
    int sv_ = (lane<m) ? csr[beg+base+lane] : 0;
    float4 as = {0,0,0,0};
    if(lane<m) as = *(const float4*)(a_s + (size_t)sv_*4);
    float pe0,pe1,pe2,pe3;
    {
      float x;
      x = as.x+ad.x; pe0 = __expf(x>0.f?x:0.2f*x);
      x = as.y+ad.y; pe1 = __expf(x>0.f?x:0.2f*x);
      x = as.z+ad.z; pe2 = __expf(x>0.f?x:0.2f*x);
      x = as.w+ad.w; pe3 = __expf(x>0.f?x:0.2f*x);
    }
    int t2=0;
    for(; t2+3<m; t2+=4){
      int s0 = __shfl(sv_, t2,   64);
      int s1 = __shfl(sv_, t2+1, 64);
      int s2 = __shfl(sv_, t2+2, 64);
      int s3 = __shfl(sv_, t2+3, 64);
      float e0 = bf2f(emat[(size_t)s0*64+lane]);
      float e1 = bf2f(emat[(size_t)s1*64+lane]);
      float e2 = bf2f(emat[(size_t)s2*64+lane]);
      float e3 = bf2f(emat[(size_t)s3*64+lane]);
      float w00=__shfl(pe0,t2,64),   w01=__shfl(pe1,t2,64),   w02=__shfl(pe2,t2,64),   w03=__shfl(pe3,t2,64);
      float w10=__shfl(pe0,t2+1,64), w11=__shfl(pe1,t2+1,64), w12=__shfl(pe2,t2+1,64), w13=__shfl(pe3,t2+1,64);
      float w20=__shfl(pe0,t2+2,64), w21=__shfl(pe1,t2+2,64), w22=__shfl(pe2,t2+2,64), w23=__shfl(pe3,t2+2,64);
      float w30=__shfl(pe0,t2+3,64), w31=__shfl(pe1,t2+3,64), w32=__shfl(pe2,t2+3,64), w33=__shfl(pe3,t2+3,64);
      c0 += w00*e0; c1 += w01*e0; c2 += w02*e0; c3 += w03*e0;
      l0 += w00;    l1 += w01;    l2 += w02;    l3 += w03;
      c0 += w10*e1; c1 += w11*e1; c2 += w12*e1; c3 += w13*e1;
      l0 += w10;    l1 += w11;    l2 += w12;    l3 += w13;
      c0 += w20*e2; c1 += w21*e2; c2 += w22*e2; c3 += w23*e2;
      l0 += w20;    l1 += w21;    l2 += w22;    l3 += w23;
      c0 += w30*e3; c1 += w31*e3; c2 += w32*e3; c3 += w33*e3;
      l0 += w30;    l1 += w31;    l2 += w32;    l3 += w33;
    }
    for(; t2<m; t2++){
      int s0 = __shfl(sv_, t2, 64);
      float e0 = bf2f(emat[(size_t)s0*64+lane]);
      float w0=__shfl(pe0,t2,64), w1=__shfl(pe1,t2,64), w2=__shfl(pe2,t2,64), w3=__shfl(pe3,t2,64);
      c0 += w0*e0; c1 += w1*e0; c2 += w2*e0; c3 += w3*e0;
      l0 += w0;    l1 += w1;    l2 += w2;    l3 += w3;
    }
  }
  aggrow[lane]       = f2bf(n>0 ? c0/l0 : 0.f);
  aggrow[64+lane]    = f2bf(n>0 ? c1/l1 : 0.f);
  aggrow[128+lane]   = f2bf(n>0 ? c2/l2 : 0.f);
  aggrow[192+lane]   = f2bf(n>0 ? c3/l3 : 0.f);
}

__global__ __launch_bounds__(512) void k6_agg(
    const int* __restrict__ off, const int* __restrict__ cnt,
    const int* __restrict__ csr_po, const int* __restrict__ csr_adj,
    const float* __restrict__ a_s_po, const float* __restrict__ a_d_po,
    const float* __restrict__ a_s_adj, const float* __restrict__ a_d_adj,
    const u16* __restrict__ e_lane, const u16* __restrict__ e_int,
    u16* __restrict__ agg)
{
  int wave=threadIdx.x>>6, lane=threadIdx.x&63;
  int d = blockIdx.x*4 + (wave&3);
  if(d>=NI) return;
  if(wave < 4){
    float4 ad = *(const float4*)(a_d_po + (size_t)d*4);
    agg_rel(off[d],    cnt[d],    lane, csr_po,  a_s_po,  ad, e_lane, agg + (size_t)d*512);
  } else {
    float4 ad = *(const float4*)(a_d_adj + (size_t)d*4);
    agg_rel(off[NI+d], cnt[NI+d], lane, csr_adj, a_s_adj, ad, e_int,  agg + (size_t)d*512 + 256);
  }
}

// ---------------- K8: A staged wave-private, B fragment-direct ----------------
__global__ __launch_bounds__(256) void k8_fused(
    const u16* __restrict__ agg, const uint4* __restrict__ WheadF,
    const float* __restrict__ bias_comb,
    const uint4* __restrict__ B2F, const float* __restrict__ bias2,
    const float* __restrict__ h0,
    const float* __restrict__ Wpi, const float* __restrict__ bpi,
    const float* __restrict__ Wv, const float* __restrict__ bvp,
    float* __restrict__ out)
{
  __shared__ u16 As[64][136];
  __shared__ u16 interT[64][264];
  int t=threadIdx.x, w=t>>6, lane=t&63;
  int r = lane&15, q = lane>>4;
  int row0 = blockIdx.x*64;

  for(int h=0;h<4;h++){
#pragma unroll
    for(int it=0; it<4; it++){
      int lrow = it*4 + q;
      int grow = row0 + w*16 + lrow;
      int arc = grow < NI ? grow : NI-1;
      int u4p = lane&15;
      int co = (u4p<8) ? (h*64 + u4p*8) : (256 + h*64 + (u4p-8)*8);
      uint4 v = *(const uint4*)(agg + (size_t)arc*512 + co);
      *(uint4*)&As[w*16 + lrow][u4p*8] = v;
    }
    __syncthreads();
    bf16x8 af[4];
#pragma unroll
    for(int kt=0;kt<4;kt++)
      af[kt] = *(const bf16x8*)&As[w*16 + r][q*8 + kt*32];
    const uint4* BF = WheadF + (size_t)h*16*64;
#pragma unroll
    for(int ct=0; ct<4; ct++){
      f32x4 facc = {0,0,0,0};
#pragma unroll
      for(int kt=0; kt<4; kt++){
        uint4 bu = BF[(kt*4 + ct)*64 + lane];
        bf16x8 bfr; *(uint4*)&bfr = bu;
        facc = __builtin_amdgcn_mfma_f32_16x16x32_bf16(af[kt], bfr, facc, 0,0,0);
      }
      int col = h*64 + ct*16 + r;
      float bcol = bias_comb[col];
#pragma unroll
      for(int rr=0; rr<4; rr++)
        interT[w*16 + q*4 + rr][col] = f2bf(fmaxf(facc[rr]+bcol, 0.f));
    }
  }
  __syncthreads();

  int arowl = w*16 + r;
  int arow  = row0 + arowl;
  int arc = arow < NI ? arow : NI-1;
  const float* h0r = h0 + (size_t)arc*64 + q*8;
  f32x4 acc[16];
#pragma unroll
  for(int i=0;i<16;i++) acc[i] = (f32x4){0,0,0,0};
#pragma unroll
  for(int ks=0; ks<10; ks++){
    bf16x8 af;
    if(ks < 8){
      af = *(const bf16x8*)&interT[arowl][ks*32 + q*8];
    } else {
      const float* hp = h0r + (ks-8)*32;
      float4 f0 = *(const float4*)(hp);
      float4 f1 = *(const float4*)(hp+4);
      uint4 P;
      P.x = pack2(f0.x,f0.y); P.y = pack2(f0.z,f0.w);
      P.z = pack2(f1.x,f1.y); P.w = pack2(f1.z,f1.w);
      *(uint4*)&af = P;
    }
    const uint4* bp = B2F + ks*1024 + lane;
#pragma unroll
    for(int tt=0;tt<16;tt++){
      uint4 bu = bp[tt*64];
      bf16x8 bfr; *(uint4*)&bfr = bu;
      acc[tt] = __builtin_amdgcn_mfma_f32_16x16x32_bf16(af, bfr, acc[tt], 0,0,0);
    }
  }
  float pk[4][8];
  float pv[4];
#pragma unroll
  for(int rr=0;rr<4;rr++){
    pv[rr]=0.f;
#pragma unroll
    for(int j=0;j<8;j++) pk[rr][j]=0.f;
  }
  int rbase = row0 + w*16 + q*4;
#pragma unroll
  for(int t2=0;t2<4;t2++){
    int c = t2*16 + r;
    float b0 = bias2[c], b1 = bias2[64+c], b2 = bias2[128+c], b3 = bias2[192+c];
    float wp[8];
#pragma unroll
    for(int j=0;j<8;j++) wp[j] = Wpi[c*8+j];
    float wv = Wv[c];
#pragma unroll
    for(int rr=0;rr<4;rr++){
      int row = rbase + rr;
      float g0 = acc[t2][rr]    + b0;
      float g1 = acc[t2+4][rr]  + b1;
      float g2 = acc[t2+8][rr]  + b2;
      float g3 = acc[t2+12][rr] + b3;
      float h0v = (row < NI) ? h0[(size_t)row*64 + c] : 0.f;
      float rg = 1.f/(1.f+__expf(-g0));
      float zg = 1.f/(1.f+__expf(-g1));
      float e2 = __expf(2.f*(g2 + rg*g3));
      float ng = 1.f - 2.f/(e2+1.f);
      float hh = (1.f-zg)*ng + zg*h0v;
      if(row < NI) out[450000 + (size_t)row*64 + c] = hh;
#pragma unroll
      for(int j=0;j<8;j++) pk[rr][j] += hh*wp[j];
      pv[rr] += hh*wv;
    }
  }
#pragma unroll
  for(int o=1;o<16;o<<=1){
#pragma unroll
    for(int rr=0;rr<4;rr++){
#pragma unroll
      for(int j=0;j<8;j++) pk[rr][j] += __shfl_xor(pk[rr][j], o, 64);
      pv[rr] += __shfl_xor(pv[rr], o, 64);
    }
  }
  if(r==0){
#pragma unroll
    for(int rr=0;rr<4;rr++){
      int row = rbase + rr;
      if(row < NI){
#pragma unroll
        for(int j=0;j<8;j++) out[(size_t)row*8 + j] = pk[rr][j] + bpi[j];
        out[400000 + row] = pv[rr] + bvp[0];
      }
    }
  }
}

extern "C" void kernel_launch(void* const* d_in, const int* in_sizes, int n_in,
                              void* d_out, int out_size, void* d_ws, size_t ws_size,
                              hipStream_t stream) {
  const float* x_int      = (const float*)d_in[0];
  const float* x_lane     = (const float*)d_in[1];
  const float* h0         = (const float*)d_in[2];
  const float* enc_int_W  = (const float*)d_in[3];
  const float* enc_int_b  = (const float*)d_in[4];
  const float* enc_lane_W = (const float*)d_in[5];
  const float* enc_lane_b = (const float*)d_in[6];
  const float* Wsrc_po    = (const float*)d_in[7];
  const float* Wdst_po    = (const float*)d_in[8];
  const float* att_src_po = (const float*)d_in[9];
  const float* att_dst_po = (const float*)d_in[10];
  const float* bias_po    = (const float*)d_in[11];
  const float* Wsrc_adj   = (const float*)d_in[12];
  const float* Wdst_adj   = (const float*)d_in[13];
  const float* att_src_adj= (const float*)d_in[14];
  const float* att_dst_adj= (const float*)d_in[15];
  const float* bias_adj   = (const float*)d_in[16];
  const float* gru_W_ih   = (const float*)d_in[17];
  const float* gru_W_hh   = (const float*)d_in[18];
  const float* gru_b_ih   = (const float*)d_in[19];
  const float* gru_b_hh   = (const float*)d_in[20];
  const float* W_pi       = (const float*)d_in[21];
  const float* b_pi       = (const float*)d_in[22];
  const float* W_v        = (const float*)d_in[23];
  const float* b_v        = (const float*)d_in[24];
  const int* src_po  = (const int*)d_in[25];
  const int* dst_po  = (const int*)d_in[26];
  const int* src_adj = (const int*)d_in[27];
  const int* dst_adj = (const int*)d_in[28];
  float* out = (float*)d_out;

  char* w = (char*)d_ws;
  size_t ofs = 0;
  auto alloc = [&](size_t bytes)->char*{
    char* p = w + ofs;
    ofs = (ofs + bytes + 255) & ~(size_t)255;
    return p;
  };
  u16*  e_lane   = (u16*)alloc((size_t)NL*64*2);
  u16*  e_int    = (u16*)alloc((size_t)NI*64*2);
  float* a_s_po  = (float*)alloc((size_t)NL*4*4);
  float* a_d_po  = (float*)alloc((size_t)NI*4*4);
  float* a_s_adj = (float*)alloc((size_t)NI*4*4);
  float* a_d_adj = (float*)alloc((size_t)NI*4*4);
  int*  cnt      = (int*)alloc((size_t)2*NI*4);
  int*  offA     = (int*)alloc((size_t)2*NI*4);
  int*  cur      = (int*)alloc((size_t)2*NI*4);
  int*  csr_po   = (int*)alloc((size_t)EPO*4);
  int*  csr_adj  = (int*)alloc((size_t)EADJ*4);
  int*  cursor   = (int*)alloc(2*4);
  u16*  agg      = (u16*)alloc((size_t)NI*512*2);
  u16*  WheadF   = (u16*)alloc(4*4*4*64*8*2);
  u16*  B2F      = (u16*)alloc(10*16*64*8*2);
  float* v4      = (float*)alloc(4*256*4);
  float* bias_comb = (float*)alloc(256*4);
  float* bias2   = (float*)alloc(256*4);
  (void)ws_size; (void)n_in; (void)in_sizes; (void)out_size;

  k0_prep<<<256, 256, 0, stream>>>(
      Wsrc_po, att_src_po, Wdst_po, att_dst_po,
      Wsrc_adj, att_src_adj, Wdst_adj, att_dst_adj,
      gru_W_ih, gru_W_hh, bias_po, bias_adj, gru_b_ih, gru_b_hh,
      v4, WheadF, B2F, bias_comb, bias2, cnt, cursor);
  k_enc<<<NLB+NIB+NHB, 256, 0, stream>>>(
      x_lane, enc_lane_W, enc_lane_b,
      x_int, enc_int_W, enc_int_b,
      v4 + 0, v4 + 256, v4 + 512, v4 + 768,
      e_lane, a_s_po, e_int, a_d_po, a_s_adj, a_d_adj,
      dst_po, dst_adj, cnt);
  k4_scan<<<dim3((NI+1023)/1024, 2), 256, 0, stream>>>(cnt, offA, cur, cursor);
  k5_scatter<<<(EPO+EADJ+255)/256, 256, 0, stream>>>(src_po, dst_po, src_adj, dst_adj,
      cur, csr_po, csr_adj);
  k6_agg<<<(NI+3)/4, 512, 0, stream>>>(offA, cnt, csr_po, csr_adj,
      a_s_po, a_d_po, a_s_adj, a_d_adj, e_lane, e_int, agg);
  k8_fused<<<(NI+63)/64, 256, 0, stream>>>(agg, (const uint4*)WheadF, bias_comb,
      (const uint4*)B2F, bias2, h0, W_pi, b_pi, W_v, b_v, out);
}